// Round 5
// baseline (183.100 us; speedup 1.0000x reference)
//
#include <hip/hip_runtime.h>

#define SEQ 2048
#define NTOK 4096
#define DIM 1024
#define FQKV 3072
#define SC_ATTN 0.08838834764831843f   // 128^-0.5
#define SC_Q (0.08838834764831843f * 1.4426950408889634f)  // fold log2e -> exp2 domain
#define SC_NORM 32.0f                  // sqrt(1024)

typedef short short8 __attribute__((ext_vector_type(8)));
typedef float f32x4 __attribute__((ext_vector_type(4)));
typedef unsigned short u16x4 __attribute__((ext_vector_type(4)));

__device__ __forceinline__ unsigned short f2bf(float f) {
    unsigned int u = __float_as_uint(f);
    u += 0x7fffu + ((u >> 16) & 1u);   // RNE
    return (unsigned short)(u >> 16);
}
__device__ __forceinline__ float bf2f(unsigned short b) {
    return __uint_as_float(((unsigned int)b) << 16);
}
__device__ __forceinline__ void gl_lds16(const void* g, void* l) {
    __builtin_amdgcn_global_load_lds((const __attribute__((address_space(1))) void*)g,
                                     (__attribute__((address_space(3))) void*)l, 16, 0, 0);
}

// ---------------------------------------------------------------------------
// L2 norm -> bf16
// ---------------------------------------------------------------------------
__global__ __launch_bounds__(256) void l2norm_bf16(const float* __restrict__ x,
                                                   const float* __restrict__ gamma,
                                                   unsigned short* __restrict__ xn) {
    int token = blockIdx.x;
    float4 v = ((const float4*)(x + (size_t)token * DIM))[threadIdx.x];
    float ss = v.x * v.x + v.y * v.y + v.z * v.z + v.w * v.w;
#pragma unroll
    for (int off = 32; off > 0; off >>= 1) ss += __shfl_down(ss, off);
    __shared__ float wsum[4];
    if ((threadIdx.x & 63) == 0) wsum[threadIdx.x >> 6] = ss;
    __syncthreads();
    float tot = wsum[0] + wsum[1] + wsum[2] + wsum[3];
    float sc = SC_NORM / fmaxf(sqrtf(tot), 1e-12f);
    float4 g = ((const float4*)gamma)[threadIdx.x];
    u16x4 o;
    o.x = f2bf(v.x * sc * g.x);
    o.y = f2bf(v.y * sc * g.y);
    o.z = f2bf(v.z * sc * g.z);
    o.w = f2bf(v.w * sc * g.w);
    ((u16x4*)(xn + (size_t)token * DIM))[threadIdx.x] = o;
}

// ---------------------------------------------------------------------------
// fp32 -> bf16 weight convert
// ---------------------------------------------------------------------------
__global__ __launch_bounds__(256) void wconv(const float* __restrict__ w,
                                             unsigned short* __restrict__ o, int n4) {
    int i = blockIdx.x * 256 + threadIdx.x;
    if (i >= n4) return;
    float4 v = ((const float4*)w)[i];
    u16x4 r;
    r.x = f2bf(v.x); r.y = f2bf(v.y); r.z = f2bf(v.z); r.w = f2bf(v.w);
    ((u16x4*)o)[i] = r;
}

// ---------------------------------------------------------------------------
// bf16 GEMM NT: C[M][N] = A[M][K] * B[N][K]^T. 128x128 tile, BK=64, 4 waves.
// Double-buffered LDS, prefetch before compute, one barrier per iter.
// C_MODE 0: f32 out. C_MODE 1: bf16 out, cols<1024 (Q) scaled by SC_Q.
// ---------------------------------------------------------------------------
template<int C_MODE>
__global__ __launch_bounds__(256) void gemm_bf16(const unsigned short* __restrict__ A,
                                                 const unsigned short* __restrict__ B,
                                                 void* __restrict__ Cv,
                                                 int M, int N, int K) {
    __shared__ unsigned short As[2][128 * 64];
    __shared__ unsigned short Bs[2][128 * 64];
    const int bn = blockIdx.x * 128, bm = blockIdx.y * 128;
    const int tid = threadIdx.x, lane = tid & 63, wv = tid >> 6;
    const int wr = wv >> 1, wc = wv & 1;
    const int l15 = lane & 15, g = lane >> 4;

    f32x4 acc[4][4] = {};

    auto stage = [&](int buf, int k0) {
#pragma unroll
        for (int inst = 0; inst < 4; ++inst) {
            int ci = inst * 256 + wv * 64 + lane;
            int row = ci >> 3, cc = ci & 7;
            int co = (cc ^ (row & 7)) << 3;
            gl_lds16(A + (size_t)(bm + row) * K + k0 + co, &As[buf][(inst * 256 + wv * 64) * 8]);
            gl_lds16(B + (size_t)(bn + row) * K + k0 + co, &Bs[buf][(inst * 256 + wv * 64) * 8]);
        }
    };

    stage(0, 0);
    __syncthreads();
    int cur = 0;
    for (int k0 = 0; k0 < K; k0 += 64) {
        if (k0 + 64 < K) stage(cur ^ 1, k0 + 64);
#pragma unroll
        for (int ks = 0; ks < 2; ++ks) {
            short8 af[4], bf[4];
#pragma unroll
            for (int f = 0; f < 4; ++f) {
                int ra = wr * 64 + f * 16 + l15;
                af[f] = *(const short8*)&As[cur][ra * 64 + (((ks * 4 + g) ^ (ra & 7)) << 3)];
                int rb = wc * 64 + f * 16 + l15;
                bf[f] = *(const short8*)&Bs[cur][rb * 64 + (((ks * 4 + g) ^ (rb & 7)) << 3)];
            }
#pragma unroll
            for (int i = 0; i < 4; ++i)
#pragma unroll
                for (int j = 0; j < 4; ++j)
                    acc[i][j] = __builtin_amdgcn_mfma_f32_16x16x32_bf16(af[i], bf[j], acc[i][j], 0, 0, 0);
        }
        __syncthreads();
        cur ^= 1;
    }

    if (C_MODE == 0) {
        float* C = (float*)Cv;
#pragma unroll
        for (int i = 0; i < 4; ++i)
#pragma unroll
            for (int j = 0; j < 4; ++j)
#pragma unroll
                for (int v = 0; v < 4; ++v) {
                    int row = bm + wr * 64 + i * 16 + g * 4 + v;
                    int col = bn + wc * 64 + j * 16 + l15;
                    C[(size_t)row * N + col] = acc[i][j][v];
                }
    } else {
        unsigned short* C = (unsigned short*)Cv;
        float s = (bn < 1024) ? SC_Q : 1.0f;
#pragma unroll
        for (int i = 0; i < 4; ++i)
#pragma unroll
            for (int j = 0; j < 4; ++j)
#pragma unroll
                for (int v = 0; v < 4; ++v) {
                    int row = bm + wr * 64 + i * 16 + g * 4 + v;
                    int col = bn + wc * 64 + j * 16 + l15;
                    C[(size_t)row * N + col] = f2bf(acc[i][j][v] * s);
                }
    }
}

// ---------------------------------------------------------------------------
// V transpose: qkv V-part [token][d] -> vt[(b*8+h)*128 + d][token]
// ---------------------------------------------------------------------------
__global__ __launch_bounds__(256) void transpose_v(const unsigned short* __restrict__ qkv,
                                                   unsigned short* __restrict__ vt) {
    __shared__ unsigned short T[64][72];
    const int t0 = blockIdx.x * 64, d0 = blockIdx.y * 64, bh = blockIdx.z;
    const int b = bh >> 3, h = bh & 7;
    const int tid = threadIdx.x;
#pragma unroll
    for (int p = 0; p < 2; ++p) {
        int r = p * 32 + (tid >> 3), c = tid & 7;
        *(short8*)&T[r][c * 8] =
            *(const short8*)(qkv + (size_t)(b * SEQ + t0 + r) * FQKV + 2048 + h * 128 + d0 + c * 8);
    }
    __syncthreads();
#pragma unroll
    for (int p = 0; p < 2; ++p) {
        int d = p * 32 + (tid >> 3), c = tid & 7;
        short8 v;
#pragma unroll
        for (int j = 0; j < 8; ++j) v[j] = (short)T[c * 8 + j][d];
        *(short8*)(vt + (size_t)(bh * 128 + d0 + d) * SEQ + t0 + c * 8) = v;
    }
}

// ---------------------------------------------------------------------------
// Flash attention, bf16 MFMA. 4 waves x 16 q-rows (QB=64), KB=64.
// Single 40KB LDS buffer, T14 reg-staged prefetch: issue next tile's global
// loads BEFORE compute, ds_write after post-compute barrier. T13 defer-max:
// skip O-rescale unless tile max exceeds running max by >16 (exp2 domain).
// Split-KV: q-blocks >=16 processed by two blocks writing fp32 partials.
// ---------------------------------------------------------------------------
__global__ __launch_bounds__(256, 4) void attn_mfma(const unsigned short* __restrict__ qkv,
                                                    const unsigned short* __restrict__ vt,
                                                    unsigned short* __restrict__ ao,
                                                    float* __restrict__ po,
                                                    float* __restrict__ pml) {
    __shared__ unsigned short Ks[64 * 128];
    __shared__ unsigned short Vs[128 * 64];
    __shared__ unsigned short Ps[4][16 * 64];
    const int h = blockIdx.y, b = blockIdx.z;
    const int x = blockIdx.x;
    int qblk, jb0, jb1, split, slot;
    if (x < 32) {                       // split blocks (qblk 16..31), longest first
        qblk = 31 - (x >> 1);
        int s = x & 1;
        int T = qblk + 1, half = (T + 1) >> 1;
        jb0 = s ? half : 0;
        jb1 = s ? T : half;
        split = 1;
        slot = ((b * 8 + h) * 16 + (qblk - 16)) * 2 + s;
    } else {                            // unsplit (qblk 15..0)
        qblk = 47 - x;
        jb0 = 0; jb1 = qblk + 1;
        split = 0; slot = 0;
    }
    const int tid = threadIdx.x, lane = tid & 63, wv = tid >> 6;
    const int l15 = lane & 15, g = lane >> 4;
    const int q0 = qblk * 64;
    const int qrow = q0 + wv * 16 + l15;

    short8 kreg[4], vreg[4];
    auto issue = [&](int jb) {
#pragma unroll
        for (int inst = 0; inst < 4; ++inst) {
            int ci = inst * 256 + tid;
            int rowk = ci >> 4, ck = ci & 15;
            kreg[inst] = *(const short8*)(qkv + (size_t)(b * SEQ + jb * 64 + rowk) * FQKV
                                          + 1024 + h * 128 + ((ck ^ (rowk & 7)) << 3));
            int rowv = ci >> 3, cv = ci & 7;
            vreg[inst] = *(const short8*)(vt + (size_t)((b * 8 + h) * 128 + rowv) * SEQ
                                          + jb * 64 + ((cv ^ (rowv & 7)) << 3));
        }
    };
    auto commit = [&]() {
#pragma unroll
        for (int inst = 0; inst < 4; ++inst) {
            int ci = inst * 256 + tid;
            *(short8*)&Ks[ci * 8] = kreg[inst];
            *(short8*)&Vs[ci * 8] = vreg[inst];
        }
    };

    // Q fragments (B-operand): lane: q = l15, d = ks*32 + g*8 + j
    short8 qf[4];
    {
        const unsigned short* qb = qkv + (size_t)(b * SEQ + qrow) * FQKV + h * 128;
#pragma unroll
        for (int ks = 0; ks < 4; ++ks) qf[ks] = *(const short8*)(qb + ks * 32 + g * 8);
    }

    float m_r = -1e30f, l_r = 0.f;
    f32x4 o[8] = {};

    issue(jb0);
    commit();
    __syncthreads();

    for (int jb = jb0; jb < jb1; ++jb) {
        if (jb + 1 < jb1) issue(jb + 1);   // loads in flight across compute

        // S^T = K * Q^T : 4 kv-fragments, accumulate over 4 d-slices
        f32x4 s[4] = {};
        __builtin_amdgcn_s_setprio(1);
#pragma unroll
        for (int ks = 0; ks < 4; ++ks) {
#pragma unroll
            for (int fi = 0; fi < 4; ++fi) {
                int rk = fi * 16 + l15;
                short8 kf = *(const short8*)&Ks[rk * 128 + (((ks * 4 + g) ^ (rk & 7)) << 3)];
                s[fi] = __builtin_amdgcn_mfma_f32_16x16x32_bf16(kf, qf[ks], s[fi], 0, 0, 0);
            }
        }
        __builtin_amdgcn_s_setprio(0);

        if (jb == qblk) {   // diagonal tile: causal mask
#pragma unroll
            for (int fi = 0; fi < 4; ++fi)
#pragma unroll
                for (int v = 0; v < 4; ++v) {
                    int kv = q0 + fi * 16 + g * 4 + v;
                    if (kv > qrow) s[fi][v] = -1e30f;
                }
        }

        // online softmax, exp2 domain, defer-max (T13)
        float mx = -1e30f;
#pragma unroll
        for (int fi = 0; fi < 4; ++fi)
            mx = fmaxf(mx, fmaxf(fmaxf(s[fi][0], s[fi][1]), fmaxf(s[fi][2], s[fi][3])));
        mx = fmaxf(mx, __shfl_xor(mx, 16));
        mx = fmaxf(mx, __shfl_xor(mx, 32));
        if (__any(mx - m_r > 16.0f)) {
            float Mn = fmaxf(m_r, mx);
            float alpha = exp2f(m_r - Mn);
            l_r *= alpha;
            float av[4];
#pragma unroll
            for (int v = 0; v < 4; ++v) av[v] = __shfl(alpha, g * 4 + v);
#pragma unroll
            for (int fn = 0; fn < 8; ++fn) {
                o[fn][0] *= av[0]; o[fn][1] *= av[1]; o[fn][2] *= av[2]; o[fn][3] *= av[3];
            }
            m_r = Mn;
        }

        float ps = 0.f;
#pragma unroll
        for (int fi = 0; fi < 4; ++fi) {
#pragma unroll
            for (int p2 = 0; p2 < 2; ++p2) {
                unsigned short b0 = f2bf(exp2f(s[fi][2 * p2] - m_r));
                unsigned short b1 = f2bf(exp2f(s[fi][2 * p2 + 1] - m_r));
                ps += bf2f(b0) + bf2f(b1);   // denominator from rounded P: consistent with PV
                int kv = fi * 16 + g * 4 + 2 * p2;
                int addr = l15 * 64 + (((kv >> 3) ^ (l15 & 7)) << 3) + (kv & 7);
                *(unsigned int*)&Ps[wv][addr] = (unsigned int)b0 | ((unsigned int)b1 << 16);
            }
        }
        ps += __shfl_xor(ps, 16);
        ps += __shfl_xor(ps, 32);
        l_r += ps;

        // O += P * V
        __builtin_amdgcn_s_setprio(1);
#pragma unroll
        for (int ks = 0; ks < 2; ++ks) {
            short8 pa = *(const short8*)&Ps[wv][l15 * 64 + (((ks * 4 + g) ^ (l15 & 7)) << 3)];
#pragma unroll
            for (int fn = 0; fn < 8; ++fn) {
                int rv = fn * 16 + l15;
                short8 vf = *(const short8*)&Vs[rv * 64 + (((ks * 4 + g) ^ (rv & 7)) << 3)];
                o[fn] = __builtin_amdgcn_mfma_f32_16x16x32_bf16(pa, vf, o[fn], 0, 0, 0);
            }
        }
        __builtin_amdgcn_s_setprio(0);

        __syncthreads();                    // all LDS reads of tile jb done
        if (jb + 1 < jb1) {
            commit();                       // write prefetched tile jb+1
            __syncthreads();                // writes visible
        }
    }

    if (split) {
        // unnormalized fp32 partial O + (m,l)
        float* od = po + (size_t)slot * (64 * 128);
#pragma unroll
        for (int fn = 0; fn < 8; ++fn)
#pragma unroll
            for (int v = 0; v < 4; ++v)
                od[(wv * 16 + g * 4 + v) * 128 + fn * 16 + l15] = o[fn][v];
        if (g == 0) {
            pml[(size_t)slot * 128 + wv * 16 + l15] = m_r;
            pml[(size_t)slot * 128 + 64 + wv * 16 + l15] = l_r;
        }
    } else {
        float lv[4];
#pragma unroll
        for (int v = 0; v < 4; ++v) lv[v] = 1.0f / __shfl(l_r, g * 4 + v);
#pragma unroll
        for (int fn = 0; fn < 8; ++fn)
#pragma unroll
            for (int v = 0; v < 4; ++v) {
                int row = b * SEQ + q0 + wv * 16 + g * 4 + v;
                ao[(size_t)row * DIM + h * 128 + fn * 16 + l15] = f2bf(o[fn][v] * lv[v]);
            }
    }
}

// ---------------------------------------------------------------------------
// Combine the two KV-split partials -> normalized bf16 output
// one block per (b,h,qblk>=16); thread: row = tid>>2, d-chunk = (tid&3)*32
// ---------------------------------------------------------------------------
__global__ __launch_bounds__(256) void attn_combine(const float* __restrict__ po,
                                                    const float* __restrict__ pml,
                                                    unsigned short* __restrict__ ao) {
    int t = blockIdx.x;                    // (b,h,qi): 256 blocks
    int qi = t & 15, h = (t >> 4) & 7, b = t >> 7;
    int qblk = 16 + qi;
    int slot0 = ((b * 8 + h) * 16 + qi) * 2;
    int row = threadIdx.x >> 2;
    int dp = threadIdx.x & 3;
    float m0 = pml[(size_t)slot0 * 128 + row];
    float l0 = pml[(size_t)slot0 * 128 + 64 + row];
    float m1 = pml[(size_t)(slot0 + 1) * 128 + row];
    float l1 = pml[(size_t)(slot0 + 1) * 128 + 64 + row];
    float M = fmaxf(m0, m1);
    float w0 = exp2f(m0 - M), w1 = exp2f(m1 - M);
    float inv = 1.0f / (w0 * l0 + w1 * l1);
    w0 *= inv; w1 *= inv;
    const float4* O0 = (const float4*)(po + (size_t)slot0 * 8192 + row * 128 + dp * 32);
    const float4* O1 = (const float4*)(po + (size_t)(slot0 + 1) * 8192 + row * 128 + dp * 32);
    unsigned short* dst = ao + ((size_t)(b * SEQ + qblk * 64 + row)) * DIM + h * 128 + dp * 32;
#pragma unroll
    for (int j = 0; j < 8; ++j) {
        float4 a = O0[j], c = O1[j];
        u16x4 r;
        r.x = f2bf(w0 * a.x + w1 * c.x);
        r.y = f2bf(w0 * a.y + w1 * c.y);
        r.z = f2bf(w0 * a.z + w1 * c.z);
        r.w = f2bf(w0 * a.w + w1 * c.w);
        *(u16x4*)(dst + j * 4) = r;
    }
}

// ---------------------------------------------------------------------------
extern "C" void kernel_launch(void* const* d_in, const int* in_sizes, int n_in,
                              void* d_out, int out_size, void* d_ws, size_t ws_size,
                              hipStream_t stream) {
    const float* x     = (const float*)d_in[0];
    const float* gamma = (const float*)d_in[1];
    const float* w_qkv = (const float*)d_in[2];
    const float* w_out = (const float*)d_in[3];

    char* ws = (char*)d_ws;
    unsigned short* qkvb = (unsigned short*)ws;                   // 25165824 B  [4096][3072]
    unsigned short* vtb  = (unsigned short*)(ws + 25165824);      //  8388608 B  [16][128][2048]
    unsigned short* xnb  = (unsigned short*)(ws + 33554432);      //  8388608 B  [4096][1024]
    unsigned short* wqb  = (unsigned short*)(ws + 41943040);      //  6291456 B  [3072][1024]
    unsigned short* wob  = (unsigned short*)(ws + 48234496);      //  2097152 B  [1024][1024]
    unsigned short* aob  = (unsigned short*)(ws + 50331648);      //  8388608 B  [4096][1024]
    float*          pml  = (float*)(ws + 58720256);               //   262144 B  [512][128]
    float*          po   = (float*)d_out;   // d_out as scratch: 512 x 64 x 128 f32 = 16.8 MB

    wconv<<<3072, 256, 0, stream>>>(w_qkv, wqb, 786432);
    wconv<<<1024, 256, 0, stream>>>(w_out, wob, 262144);
    l2norm_bf16<<<4096, 256, 0, stream>>>(x, gamma, xnb);
    gemm_bf16<1><<<dim3(24, 32), 256, 0, stream>>>(xnb, wqb, qkvb, NTOK, FQKV, DIM);
    transpose_v<<<dim3(32, 2, 16), 256, 0, stream>>>(qkvb, vtb);
    attn_mfma<<<dim3(48, 8, 2), 256, 0, stream>>>(qkvb, vtb, aob, po, pml);
    attn_combine<<<256, 256, 0, stream>>>(po, pml, aob);
    gemm_bf16<0><<<dim3(8, 32), 256, 0, stream>>>(aob, wob, (float*)d_out, NTOK, DIM, DIM);
}

// Round 6
// 147.109 us; speedup vs baseline: 1.2447x; 1.2447x over previous
//
#include <hip/hip_runtime.h>

#define SEQ 2048
#define NTOK 4096
#define DIM 1024
#define FQKV 3072
#define SC_ATTN 0.08838834764831843f   // 128^-0.5
#define SC_Q (0.08838834764831843f * 1.4426950408889634f)  // fold log2e -> exp2 domain
#define SC_NORM 32.0f                  // sqrt(1024)

typedef short short8 __attribute__((ext_vector_type(8)));
typedef float f32x4 __attribute__((ext_vector_type(4)));
typedef unsigned short u16x4 __attribute__((ext_vector_type(4)));

__device__ __forceinline__ unsigned short f2bf(float f) {
    unsigned int u = __float_as_uint(f);
    u += 0x7fffu + ((u >> 16) & 1u);   // RNE
    return (unsigned short)(u >> 16);
}
__device__ __forceinline__ float bf2f(unsigned short b) {
    return __uint_as_float(((unsigned int)b) << 16);
}
__device__ __forceinline__ void gl_lds16(const void* g, void* l) {
    __builtin_amdgcn_global_load_lds((const __attribute__((address_space(1))) void*)g,
                                     (__attribute__((address_space(3))) void*)l, 16, 0, 0);
}

// ---------------------------------------------------------------------------
// L2 norm -> bf16
// ---------------------------------------------------------------------------
__global__ __launch_bounds__(256) void l2norm_bf16(const float* __restrict__ x,
                                                   const float* __restrict__ gamma,
                                                   unsigned short* __restrict__ xn) {
    int token = blockIdx.x;
    float4 v = ((const float4*)(x + (size_t)token * DIM))[threadIdx.x];
    float ss = v.x * v.x + v.y * v.y + v.z * v.z + v.w * v.w;
#pragma unroll
    for (int off = 32; off > 0; off >>= 1) ss += __shfl_down(ss, off);
    __shared__ float wsum[4];
    if ((threadIdx.x & 63) == 0) wsum[threadIdx.x >> 6] = ss;
    __syncthreads();
    float tot = wsum[0] + wsum[1] + wsum[2] + wsum[3];
    float sc = SC_NORM / fmaxf(sqrtf(tot), 1e-12f);
    float4 g = ((const float4*)gamma)[threadIdx.x];
    u16x4 o;
    o.x = f2bf(v.x * sc * g.x);
    o.y = f2bf(v.y * sc * g.y);
    o.z = f2bf(v.z * sc * g.z);
    o.w = f2bf(v.w * sc * g.w);
    ((u16x4*)(xn + (size_t)token * DIM))[threadIdx.x] = o;
}

// ---------------------------------------------------------------------------
// fp32 -> bf16 weight convert
// ---------------------------------------------------------------------------
__global__ __launch_bounds__(256) void wconv(const float* __restrict__ w,
                                             unsigned short* __restrict__ o, int n4) {
    int i = blockIdx.x * 256 + threadIdx.x;
    if (i >= n4) return;
    float4 v = ((const float4*)w)[i];
    u16x4 r;
    r.x = f2bf(v.x); r.y = f2bf(v.y); r.z = f2bf(v.z); r.w = f2bf(v.w);
    ((u16x4*)o)[i] = r;
}

// ---------------------------------------------------------------------------
// bf16 GEMM NT: C[M][N] = A[M][K] * B[N][K]^T. 128x128 tile, BK=64, 4 waves.
// Double-buffered LDS, prefetch before compute, one barrier per iter.
// C_MODE 0: f32 out. C_MODE 1: bf16 out, cols<1024 (Q) scaled by SC_Q.
// ---------------------------------------------------------------------------
template<int C_MODE>
__global__ __launch_bounds__(256) void gemm_bf16(const unsigned short* __restrict__ A,
                                                 const unsigned short* __restrict__ B,
                                                 void* __restrict__ Cv,
                                                 int M, int N, int K) {
    __shared__ unsigned short As[2][128 * 64];
    __shared__ unsigned short Bs[2][128 * 64];
    const int bn = blockIdx.x * 128, bm = blockIdx.y * 128;
    const int tid = threadIdx.x, lane = tid & 63, wv = tid >> 6;
    const int wr = wv >> 1, wc = wv & 1;
    const int l15 = lane & 15, g = lane >> 4;

    f32x4 acc[4][4] = {};

    auto stage = [&](int buf, int k0) {
#pragma unroll
        for (int inst = 0; inst < 4; ++inst) {
            int ci = inst * 256 + wv * 64 + lane;
            int row = ci >> 3, cc = ci & 7;
            int co = (cc ^ (row & 7)) << 3;
            gl_lds16(A + (size_t)(bm + row) * K + k0 + co, &As[buf][(inst * 256 + wv * 64) * 8]);
            gl_lds16(B + (size_t)(bn + row) * K + k0 + co, &Bs[buf][(inst * 256 + wv * 64) * 8]);
        }
    };

    stage(0, 0);
    __syncthreads();
    int cur = 0;
    for (int k0 = 0; k0 < K; k0 += 64) {
        if (k0 + 64 < K) stage(cur ^ 1, k0 + 64);
#pragma unroll
        for (int ks = 0; ks < 2; ++ks) {
            short8 af[4], bf[4];
#pragma unroll
            for (int f = 0; f < 4; ++f) {
                int ra = wr * 64 + f * 16 + l15;
                af[f] = *(const short8*)&As[cur][ra * 64 + (((ks * 4 + g) ^ (ra & 7)) << 3)];
                int rb = wc * 64 + f * 16 + l15;
                bf[f] = *(const short8*)&Bs[cur][rb * 64 + (((ks * 4 + g) ^ (rb & 7)) << 3)];
            }
#pragma unroll
            for (int i = 0; i < 4; ++i)
#pragma unroll
                for (int j = 0; j < 4; ++j)
                    acc[i][j] = __builtin_amdgcn_mfma_f32_16x16x32_bf16(af[i], bf[j], acc[i][j], 0, 0, 0);
        }
        __syncthreads();
        cur ^= 1;
    }

    if (C_MODE == 0) {
        float* C = (float*)Cv;
#pragma unroll
        for (int i = 0; i < 4; ++i)
#pragma unroll
            for (int j = 0; j < 4; ++j)
#pragma unroll
                for (int v = 0; v < 4; ++v) {
                    int row = bm + wr * 64 + i * 16 + g * 4 + v;
                    int col = bn + wc * 64 + j * 16 + l15;
                    C[(size_t)row * N + col] = acc[i][j][v];
                }
    } else {
        unsigned short* C = (unsigned short*)Cv;
        float s = (bn < 1024) ? SC_Q : 1.0f;
#pragma unroll
        for (int i = 0; i < 4; ++i)
#pragma unroll
            for (int j = 0; j < 4; ++j)
#pragma unroll
                for (int v = 0; v < 4; ++v) {
                    int row = bm + wr * 64 + i * 16 + g * 4 + v;
                    int col = bn + wc * 64 + j * 16 + l15;
                    C[(size_t)row * N + col] = f2bf(acc[i][j][v] * s);
                }
    }
}

// ---------------------------------------------------------------------------
// V transpose: qkv V-part [token][d] -> vt[(b*8+h)*128 + d][token]
// ---------------------------------------------------------------------------
__global__ __launch_bounds__(256) void transpose_v(const unsigned short* __restrict__ qkv,
                                                   unsigned short* __restrict__ vt) {
    __shared__ unsigned short T[64][72];
    const int t0 = blockIdx.x * 64, d0 = blockIdx.y * 64, bh = blockIdx.z;
    const int b = bh >> 3, h = bh & 7;
    const int tid = threadIdx.x;
#pragma unroll
    for (int p = 0; p < 2; ++p) {
        int r = p * 32 + (tid >> 3), c = tid & 7;
        *(short8*)&T[r][c * 8] =
            *(const short8*)(qkv + (size_t)(b * SEQ + t0 + r) * FQKV + 2048 + h * 128 + d0 + c * 8);
    }
    __syncthreads();
#pragma unroll
    for (int p = 0; p < 2; ++p) {
        int d = p * 32 + (tid >> 3), c = tid & 7;
        short8 v;
#pragma unroll
        for (int j = 0; j < 8; ++j) v[j] = (short)T[c * 8 + j][d];
        *(short8*)(vt + (size_t)(bh * 128 + d0 + d) * SEQ + t0 + c * 8) = v;
    }
}

// ---------------------------------------------------------------------------
// Flash attention, bf16 MFMA. 4 waves x 16 q-rows (QB=64), KB=64.
// Single 40KB LDS buffer. T14 reg-staged prefetch (issue next tile's global
// loads before compute; ds_write after post-compute barrier) -- NO VGPR cap
// this time: R5's __launch_bounds__(256,4) forced 64 VGPR -> spills ->
// FETCH_SIZE +45MB. T13 defer-max. Split-KV for qblk>=16 (fp32 partials).
// ---------------------------------------------------------------------------
__global__ __launch_bounds__(256) void attn_mfma(const unsigned short* __restrict__ qkv,
                                                 const unsigned short* __restrict__ vt,
                                                 unsigned short* __restrict__ ao,
                                                 float* __restrict__ po,
                                                 float* __restrict__ pml) {
    __shared__ unsigned short Ks[64 * 128];
    __shared__ unsigned short Vs[128 * 64];
    __shared__ unsigned short Ps[4][16 * 64];
    const int h = blockIdx.y, b = blockIdx.z;
    const int x = blockIdx.x;
    int qblk, jb0, jb1, split, slot;
    if (x < 32) {                       // split blocks (qblk 16..31), longest first
        qblk = 31 - (x >> 1);
        int s = x & 1;
        int T = qblk + 1, half = (T + 1) >> 1;
        jb0 = s ? half : 0;
        jb1 = s ? T : half;
        split = 1;
        slot = ((b * 8 + h) * 16 + (qblk - 16)) * 2 + s;
    } else {                            // unsplit (qblk 15..0)
        qblk = 47 - x;
        jb0 = 0; jb1 = qblk + 1;
        split = 0; slot = 0;
    }
    const int tid = threadIdx.x, lane = tid & 63, wv = tid >> 6;
    const int l15 = lane & 15, g = lane >> 4;
    const int q0 = qblk * 64;
    const int qrow = q0 + wv * 16 + l15;

    short8 kreg[4], vreg[4];
    auto issue = [&](int jb) {
#pragma unroll
        for (int inst = 0; inst < 4; ++inst) {
            int ci = inst * 256 + tid;
            int rowk = ci >> 4, ck = ci & 15;
            kreg[inst] = *(const short8*)(qkv + (size_t)(b * SEQ + jb * 64 + rowk) * FQKV
                                          + 1024 + h * 128 + ((ck ^ (rowk & 7)) << 3));
            int rowv = ci >> 3, cv = ci & 7;
            vreg[inst] = *(const short8*)(vt + (size_t)((b * 8 + h) * 128 + rowv) * SEQ
                                          + jb * 64 + ((cv ^ (rowv & 7)) << 3));
        }
    };
    auto commit = [&]() {
#pragma unroll
        for (int inst = 0; inst < 4; ++inst) {
            int ci = inst * 256 + tid;
            *(short8*)&Ks[ci * 8] = kreg[inst];
            *(short8*)&Vs[ci * 8] = vreg[inst];
        }
    };

    // Q fragments (B-operand): lane: q = l15, d = ks*32 + g*8 + j
    short8 qf[4];
    {
        const unsigned short* qb = qkv + (size_t)(b * SEQ + qrow) * FQKV + h * 128;
#pragma unroll
        for (int ks = 0; ks < 4; ++ks) qf[ks] = *(const short8*)(qb + ks * 32 + g * 8);
    }

    float m_r = -1e30f, l_r = 0.f;
    f32x4 o[8] = {};

    issue(jb0);
    commit();
    __syncthreads();

    for (int jb = jb0; jb < jb1; ++jb) {
        if (jb + 1 < jb1) issue(jb + 1);   // loads in flight across compute

        // S^T = K * Q^T : 4 kv-fragments, accumulate over 4 d-slices
        f32x4 s[4] = {};
        __builtin_amdgcn_s_setprio(1);
#pragma unroll
        for (int ks = 0; ks < 4; ++ks) {
#pragma unroll
            for (int fi = 0; fi < 4; ++fi) {
                int rk = fi * 16 + l15;
                short8 kf = *(const short8*)&Ks[rk * 128 + (((ks * 4 + g) ^ (rk & 7)) << 3)];
                s[fi] = __builtin_amdgcn_mfma_f32_16x16x32_bf16(kf, qf[ks], s[fi], 0, 0, 0);
            }
        }
        __builtin_amdgcn_s_setprio(0);

        if (jb == qblk) {   // diagonal tile: causal mask
#pragma unroll
            for (int fi = 0; fi < 4; ++fi)
#pragma unroll
                for (int v = 0; v < 4; ++v) {
                    int kv = q0 + fi * 16 + g * 4 + v;
                    if (kv > qrow) s[fi][v] = -1e30f;
                }
        }

        // online softmax, exp2 domain, defer-max (T13)
        float mx = -1e30f;
#pragma unroll
        for (int fi = 0; fi < 4; ++fi)
            mx = fmaxf(mx, fmaxf(fmaxf(s[fi][0], s[fi][1]), fmaxf(s[fi][2], s[fi][3])));
        mx = fmaxf(mx, __shfl_xor(mx, 16));
        mx = fmaxf(mx, __shfl_xor(mx, 32));
        if (__any(mx - m_r > 16.0f)) {
            float Mn = fmaxf(m_r, mx);
            float alpha = exp2f(m_r - Mn);
            l_r *= alpha;
            float av[4];
#pragma unroll
            for (int v = 0; v < 4; ++v) av[v] = __shfl(alpha, g * 4 + v);
#pragma unroll
            for (int fn = 0; fn < 8; ++fn) {
                o[fn][0] *= av[0]; o[fn][1] *= av[1]; o[fn][2] *= av[2]; o[fn][3] *= av[3];
            }
            m_r = Mn;
        }

        float ps = 0.f;
#pragma unroll
        for (int fi = 0; fi < 4; ++fi) {
#pragma unroll
            for (int p2 = 0; p2 < 2; ++p2) {
                unsigned short b0 = f2bf(exp2f(s[fi][2 * p2] - m_r));
                unsigned short b1 = f2bf(exp2f(s[fi][2 * p2 + 1] - m_r));
                ps += bf2f(b0) + bf2f(b1);   // denominator from rounded P: consistent with PV
                int kv = fi * 16 + g * 4 + 2 * p2;
                int addr = l15 * 64 + (((kv >> 3) ^ (l15 & 7)) << 3) + (kv & 7);
                *(unsigned int*)&Ps[wv][addr] = (unsigned int)b0 | ((unsigned int)b1 << 16);
            }
        }
        ps += __shfl_xor(ps, 16);
        ps += __shfl_xor(ps, 32);
        l_r += ps;

        // O += P * V
        __builtin_amdgcn_s_setprio(1);
#pragma unroll
        for (int ks = 0; ks < 2; ++ks) {
            short8 pa = *(const short8*)&Ps[wv][l15 * 64 + (((ks * 4 + g) ^ (l15 & 7)) << 3)];
#pragma unroll
            for (int fn = 0; fn < 8; ++fn) {
                int rv = fn * 16 + l15;
                short8 vf = *(const short8*)&Vs[rv * 64 + (((ks * 4 + g) ^ (rv & 7)) << 3)];
                o[fn] = __builtin_amdgcn_mfma_f32_16x16x32_bf16(pa, vf, o[fn], 0, 0, 0);
            }
        }
        __builtin_amdgcn_s_setprio(0);

        __syncthreads();                    // all LDS reads of tile jb done
        if (jb + 1 < jb1) {
            commit();                       // write prefetched tile jb+1
            __syncthreads();                // writes visible
        }
    }

    if (split) {
        // unnormalized fp32 partial O + (m,l)
        float* od = po + (size_t)slot * (64 * 128);
#pragma unroll
        for (int fn = 0; fn < 8; ++fn)
#pragma unroll
            for (int v = 0; v < 4; ++v)
                od[(wv * 16 + g * 4 + v) * 128 + fn * 16 + l15] = o[fn][v];
        if (g == 0) {
            pml[(size_t)slot * 128 + wv * 16 + l15] = m_r;
            pml[(size_t)slot * 128 + 64 + wv * 16 + l15] = l_r;
        }
    } else {
        float lv[4];
#pragma unroll
        for (int v = 0; v < 4; ++v) lv[v] = 1.0f / __shfl(l_r, g * 4 + v);
#pragma unroll
        for (int fn = 0; fn < 8; ++fn)
#pragma unroll
            for (int v = 0; v < 4; ++v) {
                int row = b * SEQ + q0 + wv * 16 + g * 4 + v;
                ao[(size_t)row * DIM + h * 128 + fn * 16 + l15] = f2bf(o[fn][v] * lv[v]);
            }
    }
}

// ---------------------------------------------------------------------------
// Combine the two KV-split partials -> normalized bf16 output
// one block per (b,h,qblk>=16); thread: row = tid>>2, d-chunk = (tid&3)*32
// ---------------------------------------------------------------------------
__global__ __launch_bounds__(256) void attn_combine(const float* __restrict__ po,
                                                    const float* __restrict__ pml,
                                                    unsigned short* __restrict__ ao) {
    int t = blockIdx.x;                    // (b,h,qi): 256 blocks
    int qi = t & 15, h = (t >> 4) & 7, b = t >> 7;
    int qblk = 16 + qi;
    int slot0 = ((b * 8 + h) * 16 + qi) * 2;
    int row = threadIdx.x >> 2;
    int dp = threadIdx.x & 3;
    float m0 = pml[(size_t)slot0 * 128 + row];
    float l0 = pml[(size_t)slot0 * 128 + 64 + row];
    float m1 = pml[(size_t)(slot0 + 1) * 128 + row];
    float l1 = pml[(size_t)(slot0 + 1) * 128 + 64 + row];
    float M = fmaxf(m0, m1);
    float w0 = exp2f(m0 - M), w1 = exp2f(m1 - M);
    float inv = 1.0f / (w0 * l0 + w1 * l1);
    w0 *= inv; w1 *= inv;
    const float4* O0 = (const float4*)(po + (size_t)slot0 * 8192 + row * 128 + dp * 32);
    const float4* O1 = (const float4*)(po + (size_t)(slot0 + 1) * 8192 + row * 128 + dp * 32);
    unsigned short* dst = ao + ((size_t)(b * SEQ + qblk * 64 + row)) * DIM + h * 128 + dp * 32;
#pragma unroll
    for (int j = 0; j < 8; ++j) {
        float4 a = O0[j], c = O1[j];
        u16x4 r;
        r.x = f2bf(w0 * a.x + w1 * c.x);
        r.y = f2bf(w0 * a.y + w1 * c.y);
        r.z = f2bf(w0 * a.z + w1 * c.z);
        r.w = f2bf(w0 * a.w + w1 * c.w);
        *(u16x4*)(dst + j * 4) = r;
    }
}

// ---------------------------------------------------------------------------
extern "C" void kernel_launch(void* const* d_in, const int* in_sizes, int n_in,
                              void* d_out, int out_size, void* d_ws, size_t ws_size,
                              hipStream_t stream) {
    const float* x     = (const float*)d_in[0];
    const float* gamma = (const float*)d_in[1];
    const float* w_qkv = (const float*)d_in[2];
    const float* w_out = (const float*)d_in[3];

    char* ws = (char*)d_ws;
    unsigned short* qkvb = (unsigned short*)ws;                   // 25165824 B  [4096][3072]
    unsigned short* vtb  = (unsigned short*)(ws + 25165824);      //  8388608 B  [16][128][2048]
    unsigned short* xnb  = (unsigned short*)(ws + 33554432);      //  8388608 B  [4096][1024]
    unsigned short* wqb  = (unsigned short*)(ws + 41943040);      //  6291456 B  [3072][1024]
    unsigned short* wob  = (unsigned short*)(ws + 48234496);      //  2097152 B  [1024][1024]
    unsigned short* aob  = (unsigned short*)(ws + 50331648);      //  8388608 B  [4096][1024]
    float*          pml  = (float*)(ws + 58720256);               //   262144 B  [512][128]
    float*          po   = (float*)d_out;   // d_out as scratch: 512 x 64 x 128 f32 = 16.8 MB

    wconv<<<3072, 256, 0, stream>>>(w_qkv, wqb, 786432);
    wconv<<<1024, 256, 0, stream>>>(w_out, wob, 262144);
    l2norm_bf16<<<4096, 256, 0, stream>>>(x, gamma, xnb);
    gemm_bf16<1><<<dim3(24, 32), 256, 0, stream>>>(xnb, wqb, qkvb, NTOK, FQKV, DIM);
    transpose_v<<<dim3(32, 2, 16), 256, 0, stream>>>(qkvb, vtb);
    attn_mfma<<<dim3(48, 8, 2), 256, 0, stream>>>(qkvb, vtb, aob, po, pml);
    attn_combine<<<256, 256, 0, stream>>>(po, pml, aob);
    gemm_bf16<0><<<dim3(8, 32), 256, 0, stream>>>(aob, wob, (float*)d_out, NTOK, DIM, DIM);
}

// Round 7
// 123.485 us; speedup vs baseline: 1.4828x; 1.1913x over previous
//
#include <hip/hip_runtime.h>

#define SEQ 2048
#define NTOK 4096
#define DIM 1024
#define FQKV 3072
#define SC_ATTN 0.08838834764831843f   // 128^-0.5
#define SC_Q (0.08838834764831843f * 1.4426950408889634f)  // fold log2e -> exp2 domain
#define SC_NORM 32.0f                  // sqrt(1024)

typedef short short8 __attribute__((ext_vector_type(8)));
typedef float f32x4 __attribute__((ext_vector_type(4)));
typedef unsigned short u16x4 __attribute__((ext_vector_type(4)));

__device__ __forceinline__ unsigned short f2bf(float f) {
    unsigned int u = __float_as_uint(f);
    u += 0x7fffu + ((u >> 16) & 1u);   // RNE
    return (unsigned short)(u >> 16);
}
__device__ __forceinline__ void gl_lds16(const void* g, void* l) {
    __builtin_amdgcn_global_load_lds((const __attribute__((address_space(1))) void*)g,
                                     (__attribute__((address_space(3))) void*)l, 16, 0, 0);
}

// ---------------------------------------------------------------------------
// L2 norm -> bf16
// ---------------------------------------------------------------------------
__global__ __launch_bounds__(256) void l2norm_bf16(const float* __restrict__ x,
                                                   const float* __restrict__ gamma,
                                                   unsigned short* __restrict__ xn) {
    int token = blockIdx.x;
    float4 v = ((const float4*)(x + (size_t)token * DIM))[threadIdx.x];
    float ss = v.x * v.x + v.y * v.y + v.z * v.z + v.w * v.w;
#pragma unroll
    for (int off = 32; off > 0; off >>= 1) ss += __shfl_down(ss, off);
    __shared__ float wsum[4];
    if ((threadIdx.x & 63) == 0) wsum[threadIdx.x >> 6] = ss;
    __syncthreads();
    float tot = wsum[0] + wsum[1] + wsum[2] + wsum[3];
    float sc = SC_NORM / fmaxf(sqrtf(tot), 1e-12f);
    float4 g = ((const float4*)gamma)[threadIdx.x];
    u16x4 o;
    o.x = f2bf(v.x * sc * g.x);
    o.y = f2bf(v.y * sc * g.y);
    o.z = f2bf(v.z * sc * g.z);
    o.w = f2bf(v.w * sc * g.w);
    ((u16x4*)(xn + (size_t)token * DIM))[threadIdx.x] = o;
}

// ---------------------------------------------------------------------------
// fp32 -> bf16 weight convert (both weights in one launch)
// ---------------------------------------------------------------------------
__global__ __launch_bounds__(256) void wconv2(const float* __restrict__ wa, unsigned short* __restrict__ oa, int na4,
                                              const float* __restrict__ wb, unsigned short* __restrict__ ob, int nb4) {
    int i = blockIdx.x * 256 + threadIdx.x;
    const float* w; unsigned short* o; int idx;
    if (i < na4) { w = wa; o = oa; idx = i; }
    else { idx = i - na4; if (idx >= nb4) return; w = wb; o = ob; }
    float4 v = ((const float4*)w)[idx];
    u16x4 r;
    r.x = f2bf(v.x); r.y = f2bf(v.y); r.z = f2bf(v.z); r.w = f2bf(v.w);
    ((u16x4*)o)[idx] = r;
}

// ---------------------------------------------------------------------------
// bf16 GEMM NT: C[M][N] = A[M][K] * B[N][K]^T. 128x128 tile, BK=64, 4 waves.
// Double-buffered LDS, prefetch before compute, one barrier per iter.
// C_MODE 0: f32 out. C_MODE 1: bf16 out, cols<1024 (Q) scaled by SC_Q.
// ---------------------------------------------------------------------------
template<int C_MODE>
__global__ __launch_bounds__(256) void gemm_bf16(const unsigned short* __restrict__ A,
                                                 const unsigned short* __restrict__ B,
                                                 void* __restrict__ Cv,
                                                 int M, int N, int K) {
    __shared__ unsigned short As[2][128 * 64];
    __shared__ unsigned short Bs[2][128 * 64];
    const int bn = blockIdx.x * 128, bm = blockIdx.y * 128;
    const int tid = threadIdx.x, lane = tid & 63, wv = tid >> 6;
    const int wr = wv >> 1, wc = wv & 1;
    const int l15 = lane & 15, g = lane >> 4;

    f32x4 acc[4][4] = {};

    auto stage = [&](int buf, int k0) {
#pragma unroll
        for (int inst = 0; inst < 4; ++inst) {
            int ci = inst * 256 + wv * 64 + lane;
            int row = ci >> 3, cc = ci & 7;
            int co = (cc ^ (row & 7)) << 3;
            gl_lds16(A + (size_t)(bm + row) * K + k0 + co, &As[buf][(inst * 256 + wv * 64) * 8]);
            gl_lds16(B + (size_t)(bn + row) * K + k0 + co, &Bs[buf][(inst * 256 + wv * 64) * 8]);
        }
    };

    stage(0, 0);
    __syncthreads();
    int cur = 0;
    for (int k0 = 0; k0 < K; k0 += 64) {
        if (k0 + 64 < K) stage(cur ^ 1, k0 + 64);
#pragma unroll
        for (int ks = 0; ks < 2; ++ks) {
            short8 af[4], bf[4];
#pragma unroll
            for (int f = 0; f < 4; ++f) {
                int ra = wr * 64 + f * 16 + l15;
                af[f] = *(const short8*)&As[cur][ra * 64 + (((ks * 4 + g) ^ (ra & 7)) << 3)];
                int rb = wc * 64 + f * 16 + l15;
                bf[f] = *(const short8*)&Bs[cur][rb * 64 + (((ks * 4 + g) ^ (rb & 7)) << 3)];
            }
#pragma unroll
            for (int i = 0; i < 4; ++i)
#pragma unroll
                for (int j = 0; j < 4; ++j)
                    acc[i][j] = __builtin_amdgcn_mfma_f32_16x16x32_bf16(af[i], bf[j], acc[i][j], 0, 0, 0);
        }
        __syncthreads();
        cur ^= 1;
    }

    if (C_MODE == 0) {
        float* C = (float*)Cv;
#pragma unroll
        for (int i = 0; i < 4; ++i)
#pragma unroll
            for (int j = 0; j < 4; ++j)
#pragma unroll
                for (int v = 0; v < 4; ++v) {
                    int row = bm + wr * 64 + i * 16 + g * 4 + v;
                    int col = bn + wc * 64 + j * 16 + l15;
                    C[(size_t)row * N + col] = acc[i][j][v];
                }
    } else {
        unsigned short* C = (unsigned short*)Cv;
        float s = (bn < 1024) ? SC_Q : 1.0f;
#pragma unroll
        for (int i = 0; i < 4; ++i)
#pragma unroll
            for (int j = 0; j < 4; ++j)
#pragma unroll
                for (int v = 0; v < 4; ++v) {
                    int row = bm + wr * 64 + i * 16 + g * 4 + v;
                    int col = bn + wc * 64 + j * 16 + l15;
                    C[(size_t)row * N + col] = f2bf(acc[i][j][v] * s);
                }
    }
}

// ---------------------------------------------------------------------------
// V transpose: qkv V-part [token][d] -> vt[(b*8+h)*128 + d][token]
// ---------------------------------------------------------------------------
__global__ __launch_bounds__(256) void transpose_v(const unsigned short* __restrict__ qkv,
                                                   unsigned short* __restrict__ vt) {
    __shared__ unsigned short T[64][72];
    const int t0 = blockIdx.x * 64, d0 = blockIdx.y * 64, bh = blockIdx.z;
    const int b = bh >> 3, h = bh & 7;
    const int tid = threadIdx.x;
#pragma unroll
    for (int p = 0; p < 2; ++p) {
        int r = p * 32 + (tid >> 3), c = tid & 7;
        *(short8*)&T[r][c * 8] =
            *(const short8*)(qkv + (size_t)(b * SEQ + t0 + r) * FQKV + 2048 + h * 128 + d0 + c * 8);
    }
    __syncthreads();
#pragma unroll
    for (int p = 0; p < 2; ++p) {
        int d = p * 32 + (tid >> 3), c = tid & 7;
        short8 v;
#pragma unroll
        for (int j = 0; j < 8; ++j) v[j] = (short)T[c * 8 + j][d];
        *(short8*)(vt + (size_t)(bh * 128 + d0 + d) * SEQ + t0 + c * 8) = v;
    }
}

// ---------------------------------------------------------------------------
// Flash attention, bf16 MFMA. 4 waves x 16 q-rows (QB=64), KB=64.
// gl_lds staging (R4) but K and V staged in OPPOSITE phases: V(jb) flies
// under QK^T+softmax; K(jb+1) flies under PV. Each barrier's vmcnt drain
// lands after compute instead of back-to-back with the issue. 2 barriers/
// tile, 40KB LDS. T13 defer-max. Split-KV for qblk>=16 (fp32 partials).
// ---------------------------------------------------------------------------
__global__ __launch_bounds__(256) void attn_mfma(const unsigned short* __restrict__ qkv,
                                                 const unsigned short* __restrict__ vt,
                                                 unsigned short* __restrict__ ao,
                                                 float* __restrict__ po,
                                                 float* __restrict__ pml) {
    __shared__ unsigned short Ks[64 * 128];
    __shared__ unsigned short Vs[128 * 64];
    __shared__ unsigned short Ps[4][16 * 64];
    const int h = blockIdx.y, b = blockIdx.z;
    const int x = blockIdx.x;
    int qblk, jb0, jb1, split, slot;
    if (x < 32) {                       // split blocks (qblk 16..31), longest first
        qblk = 31 - (x >> 1);
        int s = x & 1;
        int T = qblk + 1, half = (T + 1) >> 1;
        jb0 = s ? half : 0;
        jb1 = s ? T : half;
        split = 1;
        slot = ((b * 8 + h) * 16 + (qblk - 16)) * 2 + s;
    } else {                            // unsplit (qblk 15..0)
        qblk = 47 - x;
        jb0 = 0; jb1 = qblk + 1;
        split = 0; slot = 0;
    }
    const int tid = threadIdx.x, lane = tid & 63, wv = tid >> 6;
    const int l15 = lane & 15, g = lane >> 4;
    const int q0 = qblk * 64;
    const int qrow = q0 + wv * 16 + l15;

    auto stageK = [&](int jb) {
#pragma unroll
        for (int inst = 0; inst < 4; ++inst) {
            int ci = inst * 256 + wv * 64 + lane;
            int rowk = ci >> 4, ck = ci & 15;
            gl_lds16(qkv + (size_t)(b * SEQ + jb * 64 + rowk) * FQKV + 1024 + h * 128
                         + ((ck ^ (rowk & 7)) << 3),
                     &Ks[(inst * 256 + wv * 64) * 8]);
        }
    };
    auto stageV = [&](int jb) {
#pragma unroll
        for (int inst = 0; inst < 4; ++inst) {
            int ci = inst * 256 + wv * 64 + lane;
            int rowv = ci >> 3, cv = ci & 7;
            gl_lds16(vt + (size_t)((b * 8 + h) * 128 + rowv) * SEQ + jb * 64
                        + ((cv ^ (rowv & 7)) << 3),
                     &Vs[(inst * 256 + wv * 64) * 8]);
        }
    };

    // Q fragments (B-operand): lane: q = l15, d = ks*32 + g*8 + j
    short8 qf[4];
    {
        const unsigned short* qb = qkv + (size_t)(b * SEQ + qrow) * FQKV + h * 128;
#pragma unroll
        for (int ks = 0; ks < 4; ++ks) qf[ks] = *(const short8*)(qb + ks * 32 + g * 8);
    }

    float m_r = -1e30f, l_r = 0.f;
    f32x4 o[8] = {};

    stageK(jb0);
    __syncthreads();                       // K(jb0) visible

    for (int jb = jb0; jb < jb1; ++jb) {
        stageV(jb);                        // flies under QK^T + softmax

        // S^T = K * Q^T : 4 kv-fragments, accumulate over 4 d-slices
        f32x4 s[4] = {};
        __builtin_amdgcn_s_setprio(1);
#pragma unroll
        for (int ks = 0; ks < 4; ++ks) {
#pragma unroll
            for (int fi = 0; fi < 4; ++fi) {
                int rk = fi * 16 + l15;
                short8 kf = *(const short8*)&Ks[rk * 128 + (((ks * 4 + g) ^ (rk & 7)) << 3)];
                s[fi] = __builtin_amdgcn_mfma_f32_16x16x32_bf16(kf, qf[ks], s[fi], 0, 0, 0);
            }
        }
        __builtin_amdgcn_s_setprio(0);

        if (jb == qblk) {   // diagonal tile: causal mask
#pragma unroll
            for (int fi = 0; fi < 4; ++fi)
#pragma unroll
                for (int v = 0; v < 4; ++v) {
                    int kv = q0 + fi * 16 + g * 4 + v;
                    if (kv > qrow) s[fi][v] = -1e30f;
                }
        }

        // online softmax, exp2 domain, defer-max (T13)
        float mx = -1e30f;
#pragma unroll
        for (int fi = 0; fi < 4; ++fi)
            mx = fmaxf(mx, fmaxf(fmaxf(s[fi][0], s[fi][1]), fmaxf(s[fi][2], s[fi][3])));
        mx = fmaxf(mx, __shfl_xor(mx, 16));
        mx = fmaxf(mx, __shfl_xor(mx, 32));
        if (__any(mx - m_r > 16.0f)) {
            float Mn = fmaxf(m_r, mx);
            float alpha = exp2f(m_r - Mn);
            l_r *= alpha;
            float av[4];
#pragma unroll
            for (int v = 0; v < 4; ++v) av[v] = __shfl(alpha, g * 4 + v);
#pragma unroll
            for (int fn = 0; fn < 8; ++fn) {
                o[fn][0] *= av[0]; o[fn][1] *= av[1]; o[fn][2] *= av[2]; o[fn][3] *= av[3];
            }
            m_r = Mn;
        }

        float ps = 0.f;
#pragma unroll
        for (int fi = 0; fi < 4; ++fi) {
#pragma unroll
            for (int p2 = 0; p2 < 2; ++p2) {
                float e0 = exp2f(s[fi][2 * p2] - m_r);
                float e1 = exp2f(s[fi][2 * p2 + 1] - m_r);
                ps += e0 + e1;             // f32 sum (bf16-rounding mismatch <= 2^-9 rel)
                unsigned short b0 = f2bf(e0), b1 = f2bf(e1);
                int kv = fi * 16 + g * 4 + 2 * p2;
                int addr = l15 * 64 + (((kv >> 3) ^ (l15 & 7)) << 3) + (kv & 7);
                *(unsigned int*)&Ps[wv][addr] = (unsigned int)b0 | ((unsigned int)b1 << 16);
            }
        }
        ps += __shfl_xor(ps, 16);
        ps += __shfl_xor(ps, 32);
        l_r += ps;

        __syncthreads();                   // V(jb) visible; all Ks reads done
        if (jb + 1 < jb1) stageK(jb + 1);  // flies under PV

        // O += P * V
        __builtin_amdgcn_s_setprio(1);
#pragma unroll
        for (int ks = 0; ks < 2; ++ks) {
            short8 pa = *(const short8*)&Ps[wv][l15 * 64 + (((ks * 4 + g) ^ (l15 & 7)) << 3)];
#pragma unroll
            for (int fn = 0; fn < 8; ++fn) {
                int rv = fn * 16 + l15;
                short8 vf = *(const short8*)&Vs[rv * 64 + (((ks * 4 + g) ^ (rv & 7)) << 3)];
                o[fn] = __builtin_amdgcn_mfma_f32_16x16x32_bf16(pa, vf, o[fn], 0, 0, 0);
            }
        }
        __builtin_amdgcn_s_setprio(0);

        __syncthreads();                   // K(jb+1) visible; all Vs reads done
    }

    if (split) {
        // unnormalized fp32 partial O + (m,l)
        float* od = po + (size_t)slot * (64 * 128);
#pragma unroll
        for (int fn = 0; fn < 8; ++fn)
#pragma unroll
            for (int v = 0; v < 4; ++v)
                od[(wv * 16 + g * 4 + v) * 128 + fn * 16 + l15] = o[fn][v];
        if (g == 0) {
            pml[(size_t)slot * 128 + wv * 16 + l15] = m_r;
            pml[(size_t)slot * 128 + 64 + wv * 16 + l15] = l_r;
        }
    } else {
        float lv[4];
#pragma unroll
        for (int v = 0; v < 4; ++v) lv[v] = 1.0f / __shfl(l_r, g * 4 + v);
#pragma unroll
        for (int fn = 0; fn < 8; ++fn)
#pragma unroll
            for (int v = 0; v < 4; ++v) {
                int row = b * SEQ + q0 + wv * 16 + g * 4 + v;
                ao[(size_t)row * DIM + h * 128 + fn * 16 + l15] = f2bf(o[fn][v] * lv[v]);
            }
    }
}

// ---------------------------------------------------------------------------
// Combine the two KV-split partials -> normalized bf16 output
// ---------------------------------------------------------------------------
__global__ __launch_bounds__(256) void attn_combine(const float* __restrict__ po,
                                                    const float* __restrict__ pml,
                                                    unsigned short* __restrict__ ao) {
    int t = blockIdx.x;                    // (b,h,qi): 256 blocks
    int qi = t & 15, h = (t >> 4) & 7, b = t >> 7;
    int qblk = 16 + qi;
    int slot0 = ((b * 8 + h) * 16 + qi) * 2;
    int row = threadIdx.x >> 2;
    int dp = threadIdx.x & 3;
    float m0 = pml[(size_t)slot0 * 128 + row];
    float l0 = pml[(size_t)slot0 * 128 + 64 + row];
    float m1 = pml[(size_t)(slot0 + 1) * 128 + row];
    float l1 = pml[(size_t)(slot0 + 1) * 128 + 64 + row];
    float M = fmaxf(m0, m1);
    float w0 = exp2f(m0 - M), w1 = exp2f(m1 - M);
    float inv = 1.0f / (w0 * l0 + w1 * l1);
    w0 *= inv; w1 *= inv;
    const float4* O0 = (const float4*)(po + (size_t)slot0 * 8192 + row * 128 + dp * 32);
    const float4* O1 = (const float4*)(po + (size_t)(slot0 + 1) * 8192 + row * 128 + dp * 32);
    unsigned short* dst = ao + ((size_t)(b * SEQ + qblk * 64 + row)) * DIM + h * 128 + dp * 32;
#pragma unroll
    for (int j = 0; j < 8; ++j) {
        float4 a = O0[j], c = O1[j];
        u16x4 r;
        r.x = f2bf(w0 * a.x + w1 * c.x);
        r.y = f2bf(w0 * a.y + w1 * c.y);
        r.z = f2bf(w0 * a.z + w1 * c.z);
        r.w = f2bf(w0 * a.w + w1 * c.w);
        *(u16x4*)(dst + j * 4) = r;
    }
}

// ---------------------------------------------------------------------------
extern "C" void kernel_launch(void* const* d_in, const int* in_sizes, int n_in,
                              void* d_out, int out_size, void* d_ws, size_t ws_size,
                              hipStream_t stream) {
    const float* x     = (const float*)d_in[0];
    const float* gamma = (const float*)d_in[1];
    const float* w_qkv = (const float*)d_in[2];
    const float* w_out = (const float*)d_in[3];

    char* ws = (char*)d_ws;
    unsigned short* qkvb = (unsigned short*)ws;                   // 25165824 B  [4096][3072]
    unsigned short* vtb  = (unsigned short*)(ws + 25165824);      //  8388608 B  [16][128][2048]
    unsigned short* xnb  = (unsigned short*)(ws + 33554432);      //  8388608 B  [4096][1024]
    unsigned short* wqb  = (unsigned short*)(ws + 41943040);      //  6291456 B  [3072][1024]
    unsigned short* wob  = (unsigned short*)(ws + 48234496);      //  2097152 B  [1024][1024]
    unsigned short* aob  = (unsigned short*)(ws + 50331648);      //  8388608 B  [4096][1024]
    float*          pml  = (float*)(ws + 58720256);               //   262144 B  [512][128]
    float*          po   = (float*)d_out;   // d_out as scratch: 512 x 64 x 128 f32 = 16.8 MB

    wconv2<<<4096, 256, 0, stream>>>(w_qkv, wqb, 786432, w_out, wob, 262144);
    l2norm_bf16<<<4096, 256, 0, stream>>>(x, gamma, xnb);
    gemm_bf16<1><<<dim3(24, 32), 256, 0, stream>>>(xnb, wqb, qkvb, NTOK, FQKV, DIM);
    transpose_v<<<dim3(32, 2, 16), 256, 0, stream>>>(qkvb, vtb);
    attn_mfma<<<dim3(48, 8, 2), 256, 0, stream>>>(qkvb, vtb, aob, po, pml);
    attn_combine<<<256, 256, 0, stream>>>(po, pml, aob);
    gemm_bf16<0><<<dim3(8, 32), 256, 0, stream>>>(aob, wob, (float*)d_out, NTOK, DIM, DIM);
}

// Round 8
// 119.872 us; speedup vs baseline: 1.5275x; 1.0301x over previous
//
#include <hip/hip_runtime.h>

#define SEQ 2048
#define NTOK 4096
#define DIM 1024
#define FQKV 3072
#define SC_ATTN 0.08838834764831843f   // 128^-0.5
#define SC_Q (0.08838834764831843f * 1.4426950408889634f)  // fold log2e -> exp2 domain
#define SC_NORM 32.0f                  // sqrt(1024)

typedef short short8 __attribute__((ext_vector_type(8)));
typedef float f32x4 __attribute__((ext_vector_type(4)));
typedef unsigned short u16x4 __attribute__((ext_vector_type(4)));

__device__ __forceinline__ unsigned short f2bf(float f) {
    unsigned int u = __float_as_uint(f);
    u += 0x7fffu + ((u >> 16) & 1u);   // RNE
    return (unsigned short)(u >> 16);
}
__device__ __forceinline__ void gl_lds16(const void* g, void* l) {
    __builtin_amdgcn_global_load_lds((const __attribute__((address_space(1))) void*)g,
                                     (__attribute__((address_space(3))) void*)l, 16, 0, 0);
}

// ---------------------------------------------------------------------------
// L2 norm -> bf16
// ---------------------------------------------------------------------------
__global__ __launch_bounds__(256) void l2norm_bf16(const float* __restrict__ x,
                                                   const float* __restrict__ gamma,
                                                   unsigned short* __restrict__ xn) {
    int token = blockIdx.x;
    float4 v = ((const float4*)(x + (size_t)token * DIM))[threadIdx.x];
    float ss = v.x * v.x + v.y * v.y + v.z * v.z + v.w * v.w;
#pragma unroll
    for (int off = 32; off > 0; off >>= 1) ss += __shfl_down(ss, off);
    __shared__ float wsum[4];
    if ((threadIdx.x & 63) == 0) wsum[threadIdx.x >> 6] = ss;
    __syncthreads();
    float tot = wsum[0] + wsum[1] + wsum[2] + wsum[3];
    float sc = SC_NORM / fmaxf(sqrtf(tot), 1e-12f);
    float4 g = ((const float4*)gamma)[threadIdx.x];
    u16x4 o;
    o.x = f2bf(v.x * sc * g.x);
    o.y = f2bf(v.y * sc * g.y);
    o.z = f2bf(v.z * sc * g.z);
    o.w = f2bf(v.w * sc * g.w);
    ((u16x4*)(xn + (size_t)token * DIM))[threadIdx.x] = o;
}

// ---------------------------------------------------------------------------
// fp32 -> bf16 weight convert (both weights in one launch)
// ---------------------------------------------------------------------------
__global__ __launch_bounds__(256) void wconv2(const float* __restrict__ wa, unsigned short* __restrict__ oa, int na4,
                                              const float* __restrict__ wb, unsigned short* __restrict__ ob, int nb4) {
    int i = blockIdx.x * 256 + threadIdx.x;
    const float* w; unsigned short* o; int idx;
    if (i < na4) { w = wa; o = oa; idx = i; }
    else { idx = i - na4; if (idx >= nb4) return; w = wb; o = ob; }
    float4 v = ((const float4*)w)[idx];
    u16x4 r;
    r.x = f2bf(v.x); r.y = f2bf(v.y); r.z = f2bf(v.z); r.w = f2bf(v.w);
    ((u16x4*)o)[idx] = r;
}

// ---------------------------------------------------------------------------
// bf16 GEMM NT: C[M][N] = A[M][K] * B[N][K]^T. TM x 128 tile, BK=64, 4 waves.
// SINGLE-buffered LDS (TM=128: 32KB -> 3 blocks/CU vs dbuf's 2): per K-step,
// read all frags to regs; lgkmcnt(0)+s_barrier; stage(k+1) into same buffer
// (covered by MFMA cluster); vmcnt(0)+s_barrier. XCD-aware block swizzle.
// C_MODE 0: f32 out. C_MODE 1: bf16 out, cols<1024 (Q) scaled by SC_Q.
// ---------------------------------------------------------------------------
template<int C_MODE, int TM>
__global__ __launch_bounds__(256) void gemm_bf16(const unsigned short* __restrict__ A,
                                                 const unsigned short* __restrict__ B,
                                                 void* __restrict__ Cv,
                                                 int M, int N, int K) {
    constexpr int MF = TM / 32;               // m-frags per wave
    __shared__ unsigned short As[TM * 64];
    __shared__ unsigned short Bs[128 * 64];

    // XCD-aware bijective swizzle (nwg % 8 == 0 for all our grids)
    int lin = blockIdx.y * gridDim.x + blockIdx.x;
    int nwg = gridDim.x * gridDim.y;
    int w = (lin & 7) * (nwg >> 3) + (lin >> 3);
    int bx = w % gridDim.x, by = w / gridDim.x;

    const int bn = bx * 128, bm = by * TM;
    const int tid = threadIdx.x, lane = tid & 63, wv = tid >> 6;
    const int wr = wv >> 1, wc = wv & 1;
    const int l15 = lane & 15, g = lane >> 4;

    f32x4 acc[MF][4] = {};

    auto stage = [&](int k0) {
#pragma unroll
        for (int ia = 0; ia < TM / 32; ++ia) {
            int ci = ia * 256 + wv * 64 + lane;
            int row = ci >> 3, cc = ci & 7;
            int co = (cc ^ (row & 7)) << 3;
            gl_lds16(A + (size_t)(bm + row) * K + k0 + co, &As[(ia * 256 + wv * 64) * 8]);
        }
#pragma unroll
        for (int ib = 0; ib < 4; ++ib) {
            int ci = ib * 256 + wv * 64 + lane;
            int row = ci >> 3, cc = ci & 7;
            int co = (cc ^ (row & 7)) << 3;
            gl_lds16(B + (size_t)(bn + row) * K + k0 + co, &Bs[(ib * 256 + wv * 64) * 8]);
        }
    };

    stage(0);
    asm volatile("s_waitcnt vmcnt(0)\ns_barrier" ::: "memory");

    for (int k0 = 0; k0 < K; k0 += 64) {
        short8 af[2][MF], bf[2][4];
#pragma unroll
        for (int ks = 0; ks < 2; ++ks) {
#pragma unroll
            for (int f = 0; f < MF; ++f) {
                int ra = wr * (TM / 2) + f * 16 + l15;
                af[ks][f] = *(const short8*)&As[ra * 64 + (((ks * 4 + g) ^ (ra & 7)) << 3)];
            }
#pragma unroll
            for (int f = 0; f < 4; ++f) {
                int rb = wc * 64 + f * 16 + l15;
                bf[ks][f] = *(const short8*)&Bs[rb * 64 + (((ks * 4 + g) ^ (rb & 7)) << 3)];
            }
        }
        // my reads landed -> signal; after barrier everyone may overwrite LDS
        asm volatile("s_waitcnt lgkmcnt(0)\ns_barrier" ::: "memory");
        if (k0 + 64 < K) stage(k0 + 64);     // flies under the MFMA cluster
#pragma unroll
        for (int ks = 0; ks < 2; ++ks)
#pragma unroll
            for (int i = 0; i < MF; ++i)
#pragma unroll
                for (int j = 0; j < 4; ++j)
                    acc[i][j] = __builtin_amdgcn_mfma_f32_16x16x32_bf16(af[ks][i], bf[ks][j], acc[i][j], 0, 0, 0);
        asm volatile("s_waitcnt vmcnt(0)\ns_barrier" ::: "memory");
    }

    if (C_MODE == 0) {
        float* C = (float*)Cv;
#pragma unroll
        for (int i = 0; i < MF; ++i)
#pragma unroll
            for (int j = 0; j < 4; ++j)
#pragma unroll
                for (int v = 0; v < 4; ++v) {
                    int row = bm + wr * (TM / 2) + i * 16 + g * 4 + v;
                    int col = bn + wc * 64 + j * 16 + l15;
                    C[(size_t)row * N + col] = acc[i][j][v];
                }
    } else {
        unsigned short* C = (unsigned short*)Cv;
        float s = (bn < 1024) ? SC_Q : 1.0f;
#pragma unroll
        for (int i = 0; i < MF; ++i)
#pragma unroll
            for (int j = 0; j < 4; ++j)
#pragma unroll
                for (int v = 0; v < 4; ++v) {
                    int row = bm + wr * (TM / 2) + i * 16 + g * 4 + v;
                    int col = bn + wc * 64 + j * 16 + l15;
                    C[(size_t)row * N + col] = f2bf(acc[i][j][v] * s);
                }
    }
}

// ---------------------------------------------------------------------------
// V transpose: qkv V-part [token][d] -> vt[(b*8+h)*128 + d][token]
// ---------------------------------------------------------------------------
__global__ __launch_bounds__(256) void transpose_v(const unsigned short* __restrict__ qkv,
                                                   unsigned short* __restrict__ vt) {
    __shared__ unsigned short T[64][72];
    const int t0 = blockIdx.x * 64, d0 = blockIdx.y * 64, bh = blockIdx.z;
    const int b = bh >> 3, h = bh & 7;
    const int tid = threadIdx.x;
#pragma unroll
    for (int p = 0; p < 2; ++p) {
        int r = p * 32 + (tid >> 3), c = tid & 7;
        *(short8*)&T[r][c * 8] =
            *(const short8*)(qkv + (size_t)(b * SEQ + t0 + r) * FQKV + 2048 + h * 128 + d0 + c * 8);
    }
    __syncthreads();
#pragma unroll
    for (int p = 0; p < 2; ++p) {
        int d = p * 32 + (tid >> 3), c = tid & 7;
        short8 v;
#pragma unroll
        for (int j = 0; j < 8; ++j) v[j] = (short)T[c * 8 + j][d];
        *(short8*)(vt + (size_t)(bh * 128 + d0 + d) * SEQ + t0 + c * 8) = v;
    }
}

// ---------------------------------------------------------------------------
// Flash attention (R7, unchanged): 4 waves x 16 q-rows, KB=64, gl_lds with
// K/V staged in opposite phases, T13 defer-max, split-KV for qblk>=16.
// ---------------------------------------------------------------------------
__global__ __launch_bounds__(256) void attn_mfma(const unsigned short* __restrict__ qkv,
                                                 const unsigned short* __restrict__ vt,
                                                 unsigned short* __restrict__ ao,
                                                 float* __restrict__ po,
                                                 float* __restrict__ pml) {
    __shared__ unsigned short Ks[64 * 128];
    __shared__ unsigned short Vs[128 * 64];
    __shared__ unsigned short Ps[4][16 * 64];
    const int h = blockIdx.y, b = blockIdx.z;
    const int x = blockIdx.x;
    int qblk, jb0, jb1, split, slot;
    if (x < 32) {
        qblk = 31 - (x >> 1);
        int s = x & 1;
        int T = qblk + 1, half = (T + 1) >> 1;
        jb0 = s ? half : 0;
        jb1 = s ? T : half;
        split = 1;
        slot = ((b * 8 + h) * 16 + (qblk - 16)) * 2 + s;
    } else {
        qblk = 47 - x;
        jb0 = 0; jb1 = qblk + 1;
        split = 0; slot = 0;
    }
    const int tid = threadIdx.x, lane = tid & 63, wv = tid >> 6;
    const int l15 = lane & 15, g = lane >> 4;
    const int q0 = qblk * 64;
    const int qrow = q0 + wv * 16 + l15;

    auto stageK = [&](int jb) {
#pragma unroll
        for (int inst = 0; inst < 4; ++inst) {
            int ci = inst * 256 + wv * 64 + lane;
            int rowk = ci >> 4, ck = ci & 15;
            gl_lds16(qkv + (size_t)(b * SEQ + jb * 64 + rowk) * FQKV + 1024 + h * 128
                         + ((ck ^ (rowk & 7)) << 3),
                     &Ks[(inst * 256 + wv * 64) * 8]);
        }
    };
    auto stageV = [&](int jb) {
#pragma unroll
        for (int inst = 0; inst < 4; ++inst) {
            int ci = inst * 256 + wv * 64 + lane;
            int rowv = ci >> 3, cv = ci & 7;
            gl_lds16(vt + (size_t)((b * 8 + h) * 128 + rowv) * SEQ + jb * 64
                        + ((cv ^ (rowv & 7)) << 3),
                     &Vs[(inst * 256 + wv * 64) * 8]);
        }
    };

    short8 qf[4];
    {
        const unsigned short* qb = qkv + (size_t)(b * SEQ + qrow) * FQKV + h * 128;
#pragma unroll
        for (int ks = 0; ks < 4; ++ks) qf[ks] = *(const short8*)(qb + ks * 32 + g * 8);
    }

    float m_r = -1e30f, l_r = 0.f;
    f32x4 o[8] = {};

    stageK(jb0);
    __syncthreads();

    for (int jb = jb0; jb < jb1; ++jb) {
        stageV(jb);

        f32x4 s[4] = {};
        __builtin_amdgcn_s_setprio(1);
#pragma unroll
        for (int ks = 0; ks < 4; ++ks) {
#pragma unroll
            for (int fi = 0; fi < 4; ++fi) {
                int rk = fi * 16 + l15;
                short8 kf = *(const short8*)&Ks[rk * 128 + (((ks * 4 + g) ^ (rk & 7)) << 3)];
                s[fi] = __builtin_amdgcn_mfma_f32_16x16x32_bf16(kf, qf[ks], s[fi], 0, 0, 0);
            }
        }
        __builtin_amdgcn_s_setprio(0);

        if (jb == qblk) {
#pragma unroll
            for (int fi = 0; fi < 4; ++fi)
#pragma unroll
                for (int v = 0; v < 4; ++v) {
                    int kv = q0 + fi * 16 + g * 4 + v;
                    if (kv > qrow) s[fi][v] = -1e30f;
                }
        }

        float mx = -1e30f;
#pragma unroll
        for (int fi = 0; fi < 4; ++fi)
            mx = fmaxf(mx, fmaxf(fmaxf(s[fi][0], s[fi][1]), fmaxf(s[fi][2], s[fi][3])));
        mx = fmaxf(mx, __shfl_xor(mx, 16));
        mx = fmaxf(mx, __shfl_xor(mx, 32));
        if (__any(mx - m_r > 16.0f)) {
            float Mn = fmaxf(m_r, mx);
            float alpha = exp2f(m_r - Mn);
            l_r *= alpha;
            float av[4];
#pragma unroll
            for (int v = 0; v < 4; ++v) av[v] = __shfl(alpha, g * 4 + v);
#pragma unroll
            for (int fn = 0; fn < 8; ++fn) {
                o[fn][0] *= av[0]; o[fn][1] *= av[1]; o[fn][2] *= av[2]; o[fn][3] *= av[3];
            }
            m_r = Mn;
        }

        float ps = 0.f;
#pragma unroll
        for (int fi = 0; fi < 4; ++fi) {
#pragma unroll
            for (int p2 = 0; p2 < 2; ++p2) {
                float e0 = exp2f(s[fi][2 * p2] - m_r);
                float e1 = exp2f(s[fi][2 * p2 + 1] - m_r);
                ps += e0 + e1;
                unsigned short b0 = f2bf(e0), b1 = f2bf(e1);
                int kv = fi * 16 + g * 4 + 2 * p2;
                int addr = l15 * 64 + (((kv >> 3) ^ (l15 & 7)) << 3) + (kv & 7);
                *(unsigned int*)&Ps[wv][addr] = (unsigned int)b0 | ((unsigned int)b1 << 16);
            }
        }
        ps += __shfl_xor(ps, 16);
        ps += __shfl_xor(ps, 32);
        l_r += ps;

        __syncthreads();
        if (jb + 1 < jb1) stageK(jb + 1);

        __builtin_amdgcn_s_setprio(1);
#pragma unroll
        for (int ks = 0; ks < 2; ++ks) {
            short8 pa = *(const short8*)&Ps[wv][l15 * 64 + (((ks * 4 + g) ^ (l15 & 7)) << 3)];
#pragma unroll
            for (int fn = 0; fn < 8; ++fn) {
                int rv = fn * 16 + l15;
                short8 vf = *(const short8*)&Vs[rv * 64 + (((ks * 4 + g) ^ (rv & 7)) << 3)];
                o[fn] = __builtin_amdgcn_mfma_f32_16x16x32_bf16(pa, vf, o[fn], 0, 0, 0);
            }
        }
        __builtin_amdgcn_s_setprio(0);

        __syncthreads();
    }

    if (split) {
        float* od = po + (size_t)slot * (64 * 128);
#pragma unroll
        for (int fn = 0; fn < 8; ++fn)
#pragma unroll
            for (int v = 0; v < 4; ++v)
                od[(wv * 16 + g * 4 + v) * 128 + fn * 16 + l15] = o[fn][v];
        if (g == 0) {
            pml[(size_t)slot * 128 + wv * 16 + l15] = m_r;
            pml[(size_t)slot * 128 + 64 + wv * 16 + l15] = l_r;
        }
    } else {
        float lv[4];
#pragma unroll
        for (int v = 0; v < 4; ++v) lv[v] = 1.0f / __shfl(l_r, g * 4 + v);
#pragma unroll
        for (int fn = 0; fn < 8; ++fn)
#pragma unroll
            for (int v = 0; v < 4; ++v) {
                int row = b * SEQ + q0 + wv * 16 + g * 4 + v;
                ao[(size_t)row * DIM + h * 128 + fn * 16 + l15] = f2bf(o[fn][v] * lv[v]);
            }
    }
}

// ---------------------------------------------------------------------------
// Combine the two KV-split partials -> normalized bf16 output
// ---------------------------------------------------------------------------
__global__ __launch_bounds__(256) void attn_combine(const float* __restrict__ po,
                                                    const float* __restrict__ pml,
                                                    unsigned short* __restrict__ ao) {
    int t = blockIdx.x;
    int qi = t & 15, h = (t >> 4) & 7, b = t >> 7;
    int qblk = 16 + qi;
    int slot0 = ((b * 8 + h) * 16 + qi) * 2;
    int row = threadIdx.x >> 2;
    int dp = threadIdx.x & 3;
    float m0 = pml[(size_t)slot0 * 128 + row];
    float l0 = pml[(size_t)slot0 * 128 + 64 + row];
    float m1 = pml[(size_t)(slot0 + 1) * 128 + row];
    float l1 = pml[(size_t)(slot0 + 1) * 128 + 64 + row];
    float M = fmaxf(m0, m1);
    float w0 = exp2f(m0 - M), w1 = exp2f(m1 - M);
    float inv = 1.0f / (w0 * l0 + w1 * l1);
    w0 *= inv; w1 *= inv;
    const float4* O0 = (const float4*)(po + (size_t)slot0 * 8192 + row * 128 + dp * 32);
    const float4* O1 = (const float4*)(po + (size_t)(slot0 + 1) * 8192 + row * 128 + dp * 32);
    unsigned short* dst = ao + ((size_t)(b * SEQ + qblk * 64 + row)) * DIM + h * 128 + dp * 32;
#pragma unroll
    for (int j = 0; j < 8; ++j) {
        float4 a = O0[j], c = O1[j];
        u16x4 r;
        r.x = f2bf(w0 * a.x + w1 * c.x);
        r.y = f2bf(w0 * a.y + w1 * c.y);
        r.z = f2bf(w0 * a.z + w1 * c.z);
        r.w = f2bf(w0 * a.w + w1 * c.w);
        *(u16x4*)(dst + j * 4) = r;
    }
}

// ---------------------------------------------------------------------------
extern "C" void kernel_launch(void* const* d_in, const int* in_sizes, int n_in,
                              void* d_out, int out_size, void* d_ws, size_t ws_size,
                              hipStream_t stream) {
    const float* x     = (const float*)d_in[0];
    const float* gamma = (const float*)d_in[1];
    const float* w_qkv = (const float*)d_in[2];
    const float* w_out = (const float*)d_in[3];

    char* ws = (char*)d_ws;
    unsigned short* qkvb = (unsigned short*)ws;                   // 25165824 B  [4096][3072]
    unsigned short* vtb  = (unsigned short*)(ws + 25165824);      //  8388608 B  [16][128][2048]
    unsigned short* xnb  = (unsigned short*)(ws + 33554432);      //  8388608 B  [4096][1024]
    unsigned short* wqb  = (unsigned short*)(ws + 41943040);      //  6291456 B  [3072][1024]
    unsigned short* wob  = (unsigned short*)(ws + 48234496);      //  2097152 B  [1024][1024]
    unsigned short* aob  = (unsigned short*)(ws + 50331648);      //  8388608 B  [4096][1024]
    float*          pml  = (float*)(ws + 58720256);               //   262144 B  [512][128]
    float*          po   = (float*)d_out;   // d_out as scratch: 512 x 64 x 128 f32 = 16.8 MB

    wconv2<<<4096, 256, 0, stream>>>(w_qkv, wqb, 786432, w_out, wob, 262144);
    l2norm_bf16<<<4096, 256, 0, stream>>>(x, gamma, xnb);
    gemm_bf16<1, 128><<<dim3(24, 32), 256, 0, stream>>>(xnb, wqb, qkvb, NTOK, FQKV, DIM);
    transpose_v<<<dim3(32, 2, 16), 256, 0, stream>>>(qkvb, vtb);
    attn_mfma<<<dim3(48, 8, 2), 256, 0, stream>>>(qkvb, vtb, aob, po, pml);
    attn_combine<<<256, 256, 0, stream>>>(po, pml, aob);
    gemm_bf16<0, 64><<<dim3(8, 64), 256, 0, stream>>>(aob, wob, (float*)d_out, NTOK, DIM, DIM);
}

// Round 9
// 118.234 us; speedup vs baseline: 1.5486x; 1.0139x over previous
//
#include <hip/hip_runtime.h>

#define SEQ 2048
#define NTOK 4096
#define DIM 1024
#define FQKV 3072
#define SC_Q (0.08838834764831843f * 1.4426950408889634f)  // 128^-.5 * log2e
#define SC_NORM 32.0f                  // sqrt(1024)

typedef short short8 __attribute__((ext_vector_type(8)));
typedef float f32x4 __attribute__((ext_vector_type(4)));
typedef unsigned short u16x4 __attribute__((ext_vector_type(4)));

__device__ __forceinline__ unsigned short f2bf(float f) {
    unsigned int u = __float_as_uint(f);
    u += 0x7fffu + ((u >> 16) & 1u);   // RNE
    return (unsigned short)(u >> 16);
}
__device__ __forceinline__ float bf2f(unsigned short b) {
    return __uint_as_float(((unsigned int)b) << 16);
}
__device__ __forceinline__ void gl_lds16(const void* g, void* l) {
    __builtin_amdgcn_global_load_lds((const __attribute__((address_space(1))) void*)g,
                                     (__attribute__((address_space(3))) void*)l, 16, 0, 0);
}

// ---------------------------------------------------------------------------
// prep: blocks [0,4096) = L2-norm per token; blocks [4096,8192) = weight conv
// ---------------------------------------------------------------------------
__global__ __launch_bounds__(256) void prep(const float* __restrict__ x,
                                            const float* __restrict__ gamma,
                                            unsigned short* __restrict__ xn,
                                            const float* __restrict__ wq,
                                            unsigned short* __restrict__ wqb,
                                            const float* __restrict__ wo,
                                            unsigned short* __restrict__ wob) {
    if (blockIdx.x < 4096) {
        int token = blockIdx.x;
        float4 v = ((const float4*)(x + (size_t)token * DIM))[threadIdx.x];
        float ss = v.x * v.x + v.y * v.y + v.z * v.z + v.w * v.w;
#pragma unroll
        for (int off = 32; off > 0; off >>= 1) ss += __shfl_down(ss, off);
        __shared__ float wsum[4];
        if ((threadIdx.x & 63) == 0) wsum[threadIdx.x >> 6] = ss;
        __syncthreads();
        float tot = wsum[0] + wsum[1] + wsum[2] + wsum[3];
        float sc = SC_NORM / fmaxf(sqrtf(tot), 1e-12f);
        float4 g = ((const float4*)gamma)[threadIdx.x];
        u16x4 o;
        o.x = f2bf(v.x * sc * g.x);
        o.y = f2bf(v.y * sc * g.y);
        o.z = f2bf(v.z * sc * g.z);
        o.w = f2bf(v.w * sc * g.w);
        ((u16x4*)(xn + (size_t)token * DIM))[threadIdx.x] = o;
    } else {
        int i = (blockIdx.x - 4096) * 256 + threadIdx.x;   // f4 index, 1048576 total
        const float* w; unsigned short* o; int idx;
        if (i < 786432) { w = wq; o = wqb; idx = i; }
        else            { w = wo; o = wob; idx = i - 786432; }
        float4 v = ((const float4*)w)[idx];
        u16x4 r;
        r.x = f2bf(v.x); r.y = f2bf(v.y); r.z = f2bf(v.z); r.w = f2bf(v.w);
        ((u16x4*)o)[idx] = r;
    }
}

// ---------------------------------------------------------------------------
// bf16 GEMM NT (R8): TM x 128 tile, BK=64, single-buffer split-phase raw
// barriers, XCD-aware bijective swizzle.
// ---------------------------------------------------------------------------
template<int C_MODE, int TM>
__global__ __launch_bounds__(256) void gemm_bf16(const unsigned short* __restrict__ A,
                                                 const unsigned short* __restrict__ B,
                                                 void* __restrict__ Cv,
                                                 int M, int N, int K) {
    constexpr int MF = TM / 32;
    __shared__ unsigned short As[TM * 64];
    __shared__ unsigned short Bs[128 * 64];

    int lin = blockIdx.y * gridDim.x + blockIdx.x;
    int nwg = gridDim.x * gridDim.y;
    int w = (lin & 7) * (nwg >> 3) + (lin >> 3);
    int bx = w % gridDim.x, by = w / gridDim.x;

    const int bn = bx * 128, bm = by * TM;
    const int tid = threadIdx.x, lane = tid & 63, wv = tid >> 6;
    const int wr = wv >> 1, wc = wv & 1;
    const int l15 = lane & 15, g = lane >> 4;

    f32x4 acc[MF][4] = {};

    auto stage = [&](int k0) {
#pragma unroll
        for (int ia = 0; ia < TM / 32; ++ia) {
            int ci = ia * 256 + wv * 64 + lane;
            int row = ci >> 3, cc = ci & 7;
            int co = (cc ^ (row & 7)) << 3;
            gl_lds16(A + (size_t)(bm + row) * K + k0 + co, &As[(ia * 256 + wv * 64) * 8]);
        }
#pragma unroll
        for (int ib = 0; ib < 4; ++ib) {
            int ci = ib * 256 + wv * 64 + lane;
            int row = ci >> 3, cc = ci & 7;
            int co = (cc ^ (row & 7)) << 3;
            gl_lds16(B + (size_t)(bn + row) * K + k0 + co, &Bs[(ib * 256 + wv * 64) * 8]);
        }
    };

    stage(0);
    asm volatile("s_waitcnt vmcnt(0)\ns_barrier" ::: "memory");

    for (int k0 = 0; k0 < K; k0 += 64) {
        short8 af[2][MF], bf[2][4];
#pragma unroll
        for (int ks = 0; ks < 2; ++ks) {
#pragma unroll
            for (int f = 0; f < MF; ++f) {
                int ra = wr * (TM / 2) + f * 16 + l15;
                af[ks][f] = *(const short8*)&As[ra * 64 + (((ks * 4 + g) ^ (ra & 7)) << 3)];
            }
#pragma unroll
            for (int f = 0; f < 4; ++f) {
                int rb = wc * 64 + f * 16 + l15;
                bf[ks][f] = *(const short8*)&Bs[rb * 64 + (((ks * 4 + g) ^ (rb & 7)) << 3)];
            }
        }
        asm volatile("s_waitcnt lgkmcnt(0)\ns_barrier" ::: "memory");
        if (k0 + 64 < K) stage(k0 + 64);
#pragma unroll
        for (int ks = 0; ks < 2; ++ks)
#pragma unroll
            for (int i = 0; i < MF; ++i)
#pragma unroll
                for (int j = 0; j < 4; ++j)
                    acc[i][j] = __builtin_amdgcn_mfma_f32_16x16x32_bf16(af[ks][i], bf[ks][j], acc[i][j], 0, 0, 0);
        asm volatile("s_waitcnt vmcnt(0)\ns_barrier" ::: "memory");
    }

    if (C_MODE == 0) {
        float* C = (float*)Cv;
#pragma unroll
        for (int i = 0; i < MF; ++i)
#pragma unroll
            for (int j = 0; j < 4; ++j)
#pragma unroll
                for (int v = 0; v < 4; ++v) {
                    int row = bm + wr * (TM / 2) + i * 16 + g * 4 + v;
                    int col = bn + wc * 64 + j * 16 + l15;
                    C[(size_t)row * N + col] = acc[i][j][v];
                }
    } else {
        unsigned short* C = (unsigned short*)Cv;
        float s = (bn < 1024) ? SC_Q : 1.0f;
#pragma unroll
        for (int i = 0; i < MF; ++i)
#pragma unroll
            for (int j = 0; j < 4; ++j)
#pragma unroll
                for (int v = 0; v < 4; ++v) {
                    int row = bm + wr * (TM / 2) + i * 16 + g * 4 + v;
                    int col = bn + wc * 64 + j * 16 + l15;
                    C[(size_t)row * N + col] = f2bf(acc[i][j][v] * s);
                }
    }
}

// ---------------------------------------------------------------------------
// V transpose: qkv V-part [token][d] -> vt[(b*8+h)*128 + d][token]
// ---------------------------------------------------------------------------
__global__ __launch_bounds__(256) void transpose_v(const unsigned short* __restrict__ qkv,
                                                   unsigned short* __restrict__ vt) {
    __shared__ unsigned short T[64][72];
    const int t0 = blockIdx.x * 64, d0 = blockIdx.y * 64, bh = blockIdx.z;
    const int b = bh >> 3, h = bh & 7;
    const int tid = threadIdx.x;
#pragma unroll
    for (int p = 0; p < 2; ++p) {
        int r = p * 32 + (tid >> 3), c = tid & 7;
        *(short8*)&T[r][c * 8] =
            *(const short8*)(qkv + (size_t)(b * SEQ + t0 + r) * FQKV + 2048 + h * 128 + d0 + c * 8);
    }
    __syncthreads();
#pragma unroll
    for (int p = 0; p < 2; ++p) {
        int d = p * 32 + (tid >> 3), c = tid & 7;
        short8 v;
#pragma unroll
        for (int j = 0; j < 8; ++j) v[j] = (short)T[c * 8 + j][d];
        *(short8*)(vt + (size_t)(bh * 128 + d0 + d) * SEQ + t0 + c * 8) = v;
    }
}

// ---------------------------------------------------------------------------
// Flash attention (R7 inner loop) with BALANCED KV-split: pieces of 5-10
// tiles. qblk 18-27 -> 3 pieces, 28-31 -> 4, 9-17 -> 2, 0-8 unsplit.
// 73 blocks per (b,h); split pieces write bf16 partial O (po, in d_out)
// + (m,l) (pml). Longest pieces scheduled first.
// ---------------------------------------------------------------------------
__global__ __launch_bounds__(256) void attn_mfma(const unsigned short* __restrict__ qkv,
                                                 const unsigned short* __restrict__ vt,
                                                 unsigned short* __restrict__ ao,
                                                 unsigned short* __restrict__ po,
                                                 float* __restrict__ pml) {
    __shared__ unsigned short Ks[64 * 128];
    __shared__ unsigned short Vs[128 * 64];
    __shared__ unsigned short Ps[4][16 * 64];
    const int h = blockIdx.y, b = blockIdx.z;
    const int x = blockIdx.x;
    int qblk, s, nsp;
    if (x < 30)      { qblk = 27 - x / 3;               s = x % 3;  nsp = 3; }
    else if (x < 46) { int i = x - 30; qblk = 31 - (i >> 2); s = i & 3; nsp = 4; }
    else if (x < 64) { int i = x - 46; qblk = 17 - (i >> 1); s = i & 1; nsp = 2; }
    else             { qblk = 72 - x;                   s = 0;      nsp = 1; }
    const int T = qblk + 1;
    const int jb0 = (s * T) / nsp, jb1 = ((s + 1) * T) / nsp;
    const int split = (nsp > 1);
    const int slot = ((b * 8 + h) << 6) + x;          // valid when split (x<64)

    const int tid = threadIdx.x, lane = tid & 63, wv = tid >> 6;
    const int l15 = lane & 15, g = lane >> 4;
    const int q0 = qblk * 64;
    const int qrow = q0 + wv * 16 + l15;

    auto stageK = [&](int jb) {
#pragma unroll
        for (int inst = 0; inst < 4; ++inst) {
            int ci = inst * 256 + wv * 64 + lane;
            int rowk = ci >> 4, ck = ci & 15;
            gl_lds16(qkv + (size_t)(b * SEQ + jb * 64 + rowk) * FQKV + 1024 + h * 128
                         + ((ck ^ (rowk & 7)) << 3),
                     &Ks[(inst * 256 + wv * 64) * 8]);
        }
    };
    auto stageV = [&](int jb) {
#pragma unroll
        for (int inst = 0; inst < 4; ++inst) {
            int ci = inst * 256 + wv * 64 + lane;
            int rowv = ci >> 3, cv = ci & 7;
            gl_lds16(vt + (size_t)((b * 8 + h) * 128 + rowv) * SEQ + jb * 64
                        + ((cv ^ (rowv & 7)) << 3),
                     &Vs[(inst * 256 + wv * 64) * 8]);
        }
    };

    short8 qf[4];
    {
        const unsigned short* qb = qkv + (size_t)(b * SEQ + qrow) * FQKV + h * 128;
#pragma unroll
        for (int ks = 0; ks < 4; ++ks) qf[ks] = *(const short8*)(qb + ks * 32 + g * 8);
    }

    float m_r = -1e30f, l_r = 0.f;
    f32x4 o[8] = {};

    stageK(jb0);
    __syncthreads();

    for (int jb = jb0; jb < jb1; ++jb) {
        stageV(jb);

        f32x4 sv[4] = {};
        __builtin_amdgcn_s_setprio(1);
#pragma unroll
        for (int ks = 0; ks < 4; ++ks) {
#pragma unroll
            for (int fi = 0; fi < 4; ++fi) {
                int rk = fi * 16 + l15;
                short8 kf = *(const short8*)&Ks[rk * 128 + (((ks * 4 + g) ^ (rk & 7)) << 3)];
                sv[fi] = __builtin_amdgcn_mfma_f32_16x16x32_bf16(kf, qf[ks], sv[fi], 0, 0, 0);
            }
        }
        __builtin_amdgcn_s_setprio(0);

        if (jb == qblk) {
#pragma unroll
            for (int fi = 0; fi < 4; ++fi)
#pragma unroll
                for (int v = 0; v < 4; ++v) {
                    int kv = q0 + fi * 16 + g * 4 + v;
                    if (kv > qrow) sv[fi][v] = -1e30f;
                }
        }

        float mx = -1e30f;
#pragma unroll
        for (int fi = 0; fi < 4; ++fi)
            mx = fmaxf(mx, fmaxf(fmaxf(sv[fi][0], sv[fi][1]), fmaxf(sv[fi][2], sv[fi][3])));
        mx = fmaxf(mx, __shfl_xor(mx, 16));
        mx = fmaxf(mx, __shfl_xor(mx, 32));
        if (__any(mx - m_r > 16.0f)) {
            float Mn = fmaxf(m_r, mx);
            float alpha = exp2f(m_r - Mn);
            l_r *= alpha;
            float av[4];
#pragma unroll
            for (int v = 0; v < 4; ++v) av[v] = __shfl(alpha, g * 4 + v);
#pragma unroll
            for (int fn = 0; fn < 8; ++fn) {
                o[fn][0] *= av[0]; o[fn][1] *= av[1]; o[fn][2] *= av[2]; o[fn][3] *= av[3];
            }
            m_r = Mn;
        }

        float ps = 0.f;
#pragma unroll
        for (int fi = 0; fi < 4; ++fi) {
#pragma unroll
            for (int p2 = 0; p2 < 2; ++p2) {
                float e0 = exp2f(sv[fi][2 * p2] - m_r);
                float e1 = exp2f(sv[fi][2 * p2 + 1] - m_r);
                ps += e0 + e1;
                unsigned short b0 = f2bf(e0), b1 = f2bf(e1);
                int kv = fi * 16 + g * 4 + 2 * p2;
                int addr = l15 * 64 + (((kv >> 3) ^ (l15 & 7)) << 3) + (kv & 7);
                *(unsigned int*)&Ps[wv][addr] = (unsigned int)b0 | ((unsigned int)b1 << 16);
            }
        }
        ps += __shfl_xor(ps, 16);
        ps += __shfl_xor(ps, 32);
        l_r += ps;

        __syncthreads();
        if (jb + 1 < jb1) stageK(jb + 1);

        __builtin_amdgcn_s_setprio(1);
#pragma unroll
        for (int ks = 0; ks < 2; ++ks) {
            short8 pa = *(const short8*)&Ps[wv][l15 * 64 + (((ks * 4 + g) ^ (l15 & 7)) << 3)];
#pragma unroll
            for (int fn = 0; fn < 8; ++fn) {
                int rv = fn * 16 + l15;
                short8 vf = *(const short8*)&Vs[rv * 64 + (((ks * 4 + g) ^ (rv & 7)) << 3)];
                o[fn] = __builtin_amdgcn_mfma_f32_16x16x32_bf16(pa, vf, o[fn], 0, 0, 0);
            }
        }
        __builtin_amdgcn_s_setprio(0);

        __syncthreads();
    }

    if (split) {
        unsigned short* od = po + (size_t)slot * 8192;   // bf16 partial O
#pragma unroll
        for (int fn = 0; fn < 8; ++fn)
#pragma unroll
            for (int v = 0; v < 4; ++v)
                od[(wv * 16 + g * 4 + v) * 128 + fn * 16 + l15] = f2bf(o[fn][v]);
        if (g == 0) {
            pml[(size_t)slot * 128 + wv * 16 + l15] = m_r;
            pml[(size_t)slot * 128 + 64 + wv * 16 + l15] = l_r;
        }
    } else {
        float lv[4];
#pragma unroll
        for (int v = 0; v < 4; ++v) lv[v] = 1.0f / __shfl(l_r, g * 4 + v);
#pragma unroll
        for (int fn = 0; fn < 8; ++fn)
#pragma unroll
            for (int v = 0; v < 4; ++v) {
                int row = b * SEQ + q0 + wv * 16 + g * 4 + v;
                ao[(size_t)row * DIM + h * 128 + fn * 16 + l15] = f2bf(o[fn][v] * lv[v]);
            }
    }
}

// ---------------------------------------------------------------------------
// Combine n in {2,3,4} KV-split partials -> normalized bf16 output.
// grid (23, 8, 2): qblk = 9 + blockIdx.x. thread: row=tid>>2, 32-d chunk.
// ---------------------------------------------------------------------------
__global__ __launch_bounds__(256) void attn_combine(const unsigned short* __restrict__ po,
                                                    const float* __restrict__ pml,
                                                    unsigned short* __restrict__ ao) {
    const int qblk = 9 + blockIdx.x, h = blockIdx.y, b = blockIdx.z;
    int base, n;
    if (qblk >= 28)      { base = 30 + (31 - qblk) * 4; n = 4; }
    else if (qblk >= 18) { base = (27 - qblk) * 3;      n = 3; }
    else                 { base = 46 + (17 - qblk) * 2; n = 2; }
    const int slot0 = ((b * 8 + h) << 6) + base;
    const int row = threadIdx.x >> 2, dp = threadIdx.x & 3;

    float M = -1e30f;
#pragma unroll
    for (int s2 = 0; s2 < 4; ++s2)
        if (s2 < n) M = fmaxf(M, pml[(size_t)(slot0 + s2) * 128 + row]);
    float denom = 0.f;
#pragma unroll
    for (int s2 = 0; s2 < 4; ++s2)
        if (s2 < n) denom += exp2f(pml[(size_t)(slot0 + s2) * 128 + row] - M)
                             * pml[(size_t)(slot0 + s2) * 128 + 64 + row];
    float inv = 1.0f / denom;

    float acc[32] = {};
#pragma unroll
    for (int s2 = 0; s2 < 4; ++s2)
        if (s2 < n) {
            float wgt = exp2f(pml[(size_t)(slot0 + s2) * 128 + row] - M) * inv;
            const unsigned short* ob = po + (size_t)(slot0 + s2) * 8192 + row * 128 + dp * 32;
#pragma unroll
            for (int j = 0; j < 4; ++j) {
                short8 pv = *(const short8*)(ob + j * 8);
#pragma unroll
                for (int e = 0; e < 8; ++e)
                    acc[j * 8 + e] += wgt * bf2f((unsigned short)pv[e]);
            }
        }

    unsigned short* dst = ao + ((size_t)(b * SEQ + qblk * 64 + row)) * DIM + h * 128 + dp * 32;
#pragma unroll
    for (int j = 0; j < 4; ++j) {
        short8 r;
#pragma unroll
        for (int e = 0; e < 8; ++e) r[e] = (short)f2bf(acc[j * 8 + e]);
        *(short8*)(dst + j * 8) = r;
    }
}

// ---------------------------------------------------------------------------
extern "C" void kernel_launch(void* const* d_in, const int* in_sizes, int n_in,
                              void* d_out, int out_size, void* d_ws, size_t ws_size,
                              hipStream_t stream) {
    const float* x     = (const float*)d_in[0];
    const float* gamma = (const float*)d_in[1];
    const float* w_qkv = (const float*)d_in[2];
    const float* w_out = (const float*)d_in[3];

    char* ws = (char*)d_ws;
    unsigned short* qkvb = (unsigned short*)ws;                   // 25165824 B  [4096][3072]
    unsigned short* vtb  = (unsigned short*)(ws + 25165824);      //  8388608 B  [16][128][2048]
    unsigned short* xnb  = (unsigned short*)(ws + 33554432);      //  8388608 B  [4096][1024]
    unsigned short* wqb  = (unsigned short*)(ws + 41943040);      //  6291456 B  [3072][1024]
    unsigned short* wob  = (unsigned short*)(ws + 48234496);      //  2097152 B  [1024][1024]
    unsigned short* aob  = (unsigned short*)(ws + 50331648);      //  8388608 B  [4096][1024]
    // pml overlaps wqb: gemm1 (reader of wqb) completes before attn writes pml
    float*          pml  = (float*)(ws + 41943040);               //   524288 B  [1024][128]
    unsigned short* po   = (unsigned short*)d_out;  // 1024 slots x 64x128 bf16 = 16.8 MB

    prep<<<8192, 256, 0, stream>>>(x, gamma, xnb, w_qkv, wqb, w_out, wob);
    gemm_bf16<1, 128><<<dim3(24, 32), 256, 0, stream>>>(xnb, wqb, qkvb, NTOK, FQKV, DIM);
    transpose_v<<<dim3(32, 2, 16), 256, 0, stream>>>(qkvb, vtb);
    attn_mfma<<<dim3(73, 8, 2), 256, 0, stream>>>(qkvb, vtb, aob, po, pml);
    attn_combine<<<dim3(23, 8, 2), 256, 0, stream>>>(po, pml, aob);
    gemm_bf16<0, 64><<<dim3(8, 64), 256, 0, stream>>>(aob, wob, (float*)d_out, NTOK, DIM, DIM);
}